// Round 10
// baseline (916.007 us; speedup 1.0000x reference)
//
#include <hip/hip_runtime.h>
#include <stdint.h>

typedef unsigned int u32;
typedef unsigned short u16;
typedef unsigned long long u64;
typedef __attribute__((ext_vector_type(8))) short bf16x8;
typedef __attribute__((ext_vector_type(4))) float f32x4;

#define HC 32
#define CPT 16   // points per wave in conv kernels

__device__ __forceinline__ float u2f(u32 u){ union{u32 i;float f;}v; v.i=u; return v.f; }
__device__ __forceinline__ u16 f2bf(float f){ union{float f;u32 i;}v; v.f=f; u32 i=v.i;
    return (u16)((i + 0x7FFFu + ((i>>16)&1u))>>16); }  // RNE
__device__ __forceinline__ short bfs(float f){ return (short)f2bf(f); }
__device__ __forceinline__ u32 packbf(float a, float b){ return (u32)f2bf(a) | ((u32)f2bf(b)<<16); }

// stage 26 sparse k-slices (skip k=13), bf16x2 c-pairs: wl[kp*512 + (h*8+cc2)*32 + o]
__device__ __forceinline__ void stage_w26(const float* __restrict__ W, u32* __restrict__ wl, int nthr) {
    for (int i = threadIdx.x; i < 26*512; i += nthr) {
        int o = i & 31, row = (i >> 5) & 15, kp = i >> 9;
        int k = kp + (kp >= 13 ? 1 : 0);
        int c0 = (row >> 3)*16 + (row & 7)*2;
        wl[i] = packbf(W[k*1024 + c0*32 + o], W[k*1024 + (c0+1)*32 + o]);
    }
}

// stage ALL 27 k-slices (incl. self), same layout: wl[k*512 + (h*8+cc2)*32 + o]
__device__ __forceinline__ void stage_w27(const float* __restrict__ W, u32* __restrict__ wl, int nthr) {
    for (int i = threadIdx.x; i < 27*512; i += nthr) {
        int o = i & 31, row = (i >> 5) & 15, k = i >> 9;
        int c0 = (row >> 3)*16 + (row & 7)*2;
        wl[i] = packbf(W[k*1024 + c0*32 + o], W[k*1024 + (c0+1)*32 + o]);
    }
}

// ---- K1: y = x @ Wg1 + bg1 -> cv | gl  (MFMA) ----
__global__ __launch_bounds__(256) void k1_mfma(
    const float* __restrict__ x, const float* __restrict__ Wg1, const float* __restrict__ bg1,
    float* __restrict__ cv, float* __restrict__ gl, long long N)
{
    const int lane = threadIdx.x & 63;
    const int m = lane & 15, g = lane >> 4;
    bf16x8 bw[4][2];
    #pragma unroll
    for (int no = 0; no < 4; ++no)
      #pragma unroll
      for (int kf = 0; kf < 2; ++kf)
        #pragma unroll
        for (int j = 0; j < 8; ++j)
            bw[no][kf][j] = bfs(Wg1[(kf*32 + g*8 + j)*64 + no*16 + m]);
    float bias4[4];
    #pragma unroll
    for (int no = 0; no < 4; ++no) bias4[no] = bg1[no*16 + m];

    const long long wave = (long long)blockIdx.x*4 + (threadIdx.x>>6);
    long long t0 = wave * 4;
    #pragma unroll 1
    for (long long t = t0; t < t0+4; ++t) {
        long long p0 = t*16;
        if (p0 >= N) break;
        long long pr_a = p0 + m; if (pr_a > N-1) pr_a = N-1;
        const float4* xr = (const float4*)(x + pr_a*64);
        bf16x8 aw[2];
        #pragma unroll
        for (int kf = 0; kf < 2; ++kf) {
            float4 lo = xr[kf*8 + g*2];
            float4 hi = xr[kf*8 + g*2 + 1];
            aw[kf][0]=bfs(lo.x); aw[kf][1]=bfs(lo.y); aw[kf][2]=bfs(lo.z); aw[kf][3]=bfs(lo.w);
            aw[kf][4]=bfs(hi.x); aw[kf][5]=bfs(hi.y); aw[kf][6]=bfs(hi.z); aw[kf][7]=bfs(hi.w);
        }
        #pragma unroll
        for (int no = 0; no < 4; ++no) {
            f32x4 acc = {0.f,0.f,0.f,0.f};
            acc = __builtin_amdgcn_mfma_f32_16x16x32_bf16(aw[0], bw[no][0], acc, 0,0,0);
            acc = __builtin_amdgcn_mfma_f32_16x16x32_bf16(aw[1], bw[no][1], acc, 0,0,0);
            #pragma unroll
            for (int j = 0; j < 4; ++j) {
                long long pr = p0 + g*4 + j;
                if (pr < N) {
                    float v = acc[j] + bias4[no];
                    if (no < 2) cv[pr*32 + no*16 + m] = v;
                    else        gl[pr*32 + (no-2)*16 + m] = v;
                }
            }
        }
    }
}

// ---- K2 fused: r1 = relu(sconv(cv,Wr1)+br1); out1/out2 = relu(sconv(gl,Wq1/Wq2));
//      Wr1 fully in LDS (27 slices incl. self); Wq self in 16 regs ----
__global__ __launch_bounds__(1024, 1) void k2_fused(
    const float* __restrict__ cv, const float* __restrict__ gl,
    const int* __restrict__ nbr, const int* __restrict__ batch_id,
    const float* __restrict__ Wr1, const float* __restrict__ br1,
    const float* __restrict__ Wq1, const float* __restrict__ bq1,
    const float* __restrict__ Wq2, const float* __restrict__ bq2,
    float* __restrict__ r1, float* __restrict__ s12, float* __restrict__ m1,
    float* __restrict__ bsum, long long N)
{
    __shared__ u32 wr[27*512];    // Wr1 all 27 slices, bf16x2 c-pairs
    __shared__ u32 wq[26*1024];   // (Wq1,Wq2) packed per (c,o), sparse 26
    __shared__ float lbs[128];
    stage_w27(Wr1, wr, 1024);
    for (int i = threadIdx.x; i < 26*1024; i += 1024) {
        int o = i & 31, c = (i >> 5) & 31, kp = i >> 10;
        int k = kp + (kp >= 13 ? 1 : 0);
        wq[i] = packbf(Wq1[k*1024 + c*32 + o], Wq2[k*1024 + c*32 + o]);
    }
    if (threadIdx.x < 128) lbs[threadIdx.x] = 0.f;
    __syncthreads();

    const int lane = threadIdx.x & 63, o = lane & 31, h = lane >> 5;
    const bool idxlane = (lane < 27 && lane != 13);
    u32 wsq[16];   // packed (Wq1,Wq2) k=13 self weights
    #pragma unroll
    for (int cc = 0; cc < 16; ++cc)
        wsq[cc] = packbf(Wq1[13*1024 + (h*16+cc)*32 + o], Wq2[13*1024 + (h*16+cc)*32 + o]);
    const float brv = br1[o], b1 = bq1[o], b2 = bq2[o];

    const long long wave = (long long)blockIdx.x*16 + (threadIdx.x>>6);
    long long n0 = wave*CPT, n1 = n0+CPT; if (n1 > N) n1 = N;
    if (n0 >= n1) return;

    // prime pipeline: idx(n0), idx(n0+1), self rows(n0), first-2 gather rows(n0)
    int ia = idxlane ? nbr[(long long)lane*N + n0] : -1;
    int ib = (n0+1 < n1 && idxlane) ? nbr[(long long)lane*N + n0+1] : -1;
    u32 ma = (u32)__ballot(ia >= 0);
    float sac = cv[n0*HC + o], sag = gl[n0*HC + o];
    float rac0 = 0.f, rag0 = 0.f, rac1 = 0.f, rag1 = 0.f;
    if (ma) {
        int k0 = (int)__builtin_ctz(ma);
        long long i0 = (long long)__shfl(ia, k0, 64);
        rac0 = cv[i0*HC + o]; rag0 = gl[i0*HC + o];
        u32 m2 = ma & (ma-1);
        if (m2) {
            long long i1 = (long long)__shfl(ia, (int)__builtin_ctz(m2), 64);
            rac1 = cv[i1*HC + o]; rag1 = gl[i1*HC + o];
        }
    }

    for (long long n = n0; n < n1; ++n) {
        // prefetch point n+1 (ballot + self rows + first-2 gathers), idx for n+2
        u32 mb = 0; float rbc0=0.f, rbg0=0.f, rbc1=0.f, rbg1=0.f, sbc=0.f, sbg=0.f;
        int ic = -1;
        if (n+1 < n1) {
            mb = (u32)__ballot(ib >= 0);
            sbc = cv[(n+1)*HC + o]; sbg = gl[(n+1)*HC + o];
            if (mb) {
                int k0 = (int)__builtin_ctz(mb);
                long long i0 = (long long)__shfl(ib, k0, 64);
                rbc0 = cv[i0*HC + o]; rbg0 = gl[i0*HC + o];
                u32 m2 = mb & (mb-1);
                if (m2) {
                    long long i1 = (long long)__shfl(ib, (int)__builtin_ctz(m2), 64);
                    rbc1 = cv[i1*HC + o]; rbg1 = gl[i1*HC + o];
                }
            }
            if (n+2 < n1) ic = idxlane ? nbr[(long long)lane*N + n+2] : -1;
        }
        // ---- compute point n ----
        float accr = 0.f, acc1 = 0.f, acc2 = 0.f;
        // r self (k=13) from LDS
        {
            const u32* wpr = wr + 13*512 + h*256 + o;
            #pragma unroll
            for (int cc2 = 0; cc2 < 8; ++cc2) {
                u32 wv = wpr[cc2*32];
                float xv0 = __shfl(sac, h*16 + 2*cc2, 64);
                float xv1 = __shfl(sac, h*16 + 2*cc2 + 1, 64);
                accr = fmaf(u2f(wv << 16), xv0, accr);
                accr = fmaf(u2f(wv & 0xffff0000u), xv1, accr);
            }
        }
        // q self (k=13) from regs
        #pragma unroll
        for (int cc = 0; cc < 16; ++cc) {
            u32 wv = wsq[cc];
            float xv = __shfl(sag, h*16 + cc, 64);
            acc1 = fmaf(u2f(wv << 16), xv, acc1);
            acc2 = fmaf(u2f(wv & 0xffff0000u), xv, acc2);
        }
        // sparse neighbors (both paths share idx/mask)
        u32 mm = ma; int j = 0;
        while (mm) {
            int k = (int)__builtin_ctz(mm); mm &= mm-1;
            float rc, rg;
            if (j == 0)      { rc = rac0; rg = rag0; }
            else if (j == 1) { rc = rac1; rg = rag1; }
            else { long long ii = (long long)__shfl(ia, k, 64);
                   rc = cv[ii*HC + o]; rg = gl[ii*HC + o]; }
            int ks = k - (k > 13 ? 1 : 0);
            const u32* wpr = wr + k*512 + h*256 + o;
            const u32* wpq = wq + ks*1024 + h*512 + o;
            #pragma unroll
            for (int cc2 = 0; cc2 < 8; ++cc2) {
                u32 wv = wpr[cc2*32];
                float xv0 = __shfl(rc, h*16 + 2*cc2, 64);
                float xv1 = __shfl(rc, h*16 + 2*cc2 + 1, 64);
                accr = fmaf(u2f(wv << 16), xv0, accr);
                accr = fmaf(u2f(wv & 0xffff0000u), xv1, accr);
            }
            #pragma unroll
            for (int cc = 0; cc < 16; ++cc) {
                u32 wv = wpq[cc*32];
                float xv = __shfl(rg, h*16 + cc, 64);
                acc1 = fmaf(u2f(wv << 16), xv, acc1);
                acc2 = fmaf(u2f(wv & 0xffff0000u), xv, acc2);
            }
            ++j;
        }
        accr += __shfl_xor(accr, 32, 64);
        acc1 += __shfl_xor(acc1, 32, 64);
        acc2 += __shfl_xor(acc2, 32, 64);
        float rv = fmaxf(accr + brv, 0.f);
        float o1 = fmaxf(acc1 + b1, 0.f);
        float o2 = fmaxf(acc2 + b2, 0.f);
        float sm = o1;
        #pragma unroll
        for (int d = 1; d < 32; d <<= 1) sm += __shfl_xor(sm, d, 64);
        int b = batch_id[n];
        if (lane < HC) {
            r1[n*HC + o] = rv;
            s12[n*HC + o] = o1 + o2;
            atomicAdd(&lbs[b*HC + o], o2);
        }
        if (lane == 0) m1[n] = sm * (1.f/32.f);
        // rotate pipeline
        ia = ib; ib = ic; ma = mb;
        rac0 = rbc0; rag0 = rbg0; rac1 = rbc1; rag1 = rbg1;
        sac = sbc; sag = sbg;
    }
    __syncthreads();
    if (threadIdx.x < 128) atomicAdd(&bsum[threadIdx.x], lbs[threadIdx.x]);
}

// ---- K3 fused: r2-conv -> cx2 tile in LDS -> MFMA epilogue -> out ----
__global__ __launch_bounds__(512, 1) void k3_fused(
    const float* __restrict__ r1, const float* __restrict__ cv,
    const float* __restrict__ gl, const float* __restrict__ s12,
    const float* __restrict__ m1, const float* __restrict__ bsum,
    const int* __restrict__ nbr, const int* __restrict__ batch_id,
    const float* __restrict__ Wr2, const float* __restrict__ br2,
    const float* __restrict__ Wq3, const float* __restrict__ bq3,
    const float* __restrict__ Wg2, const float* __restrict__ bg2,
    const float* __restrict__ x, float* __restrict__ out,
    long long N, const int* __restrict__ bsz)
{
    __shared__ u32 wr[26*512];
    __shared__ __align__(16) u16 finL[8][16*40];
    __shared__ __align__(16) u16 a2L[8][16*72];
    stage_w26(Wr2, wr, 512);
    __syncthreads();

    const int wid = threadIdx.x >> 6;
    u16* fin_bf = finL[wid];
    u16* a2_bf  = a2L[wid];
    const int lane = threadIdx.x & 63, o = lane & 31, h = lane >> 5;
    const int m = lane & 15, g = lane >> 4;
    const bool idxlane = (lane < 27 && lane != 13);

    u32 wsr[8];
    #pragma unroll
    for (int cc2 = 0; cc2 < 8; ++cc2)
        wsr[cc2] = packbf(Wr2[13*1024 + (h*16+2*cc2)*32 + o], Wr2[13*1024 + (h*16+2*cc2+1)*32 + o]);
    const float brv = br2[o];

    const long long wave = (long long)blockIdx.x*8 + wid;
    const long long p0 = wave*CPT;
    long long n0 = p0, n1 = n0+CPT; if (n1 > N) n1 = N;

    // conv phase: cx2 = relu(sconv(r1,Wr2)+br2) + 2*cv -> a2 tile (bf16)
    int cidx = -1; float pself = 0.f, pcv = 0.f;
    if (n0 < n1) {
        cidx = idxlane ? nbr[(long long)lane*N + n0] : -1;
        pself = r1[n0*HC + o]; pcv = cv[n0*HC + o];
    }
    for (long long n = n0; n < n1; ++n) {
        int idxv = cidx;
        float selfv = pself, cvv = pcv;
        u32 mask = (u32)__ballot(idxv >= 0);
        float rr0=0.f, rr1=0.f;
        if (mask) {
            int k0 = (int)__builtin_ctz(mask);
            rr0 = r1[(long long)__shfl(idxv, k0, 64)*HC + o];
            u32 m2 = mask & (mask-1);
            if (m2) rr1 = r1[(long long)__shfl(idxv, (int)__builtin_ctz(m2), 64)*HC + o];
        }
        if (n+1 < n1) {
            cidx = idxlane ? nbr[(long long)lane*N + n+1] : -1;
            pself = r1[(n+1)*HC + o]; pcv = cv[(n+1)*HC + o];
        }
        float acc = 0.f;
        #pragma unroll
        for (int cc2 = 0; cc2 < 8; ++cc2) {
            u32 wv = wsr[cc2];
            float xv0 = __shfl(selfv, h*16 + 2*cc2, 64);
            float xv1 = __shfl(selfv, h*16 + 2*cc2 + 1, 64);
            acc = fmaf(u2f(wv << 16), xv0, acc);
            acc = fmaf(u2f(wv & 0xffff0000u), xv1, acc);
        }
        u32 mm = mask; int j = 0;
        while (mm) {
            int k = (int)__builtin_ctz(mm); mm &= mm-1;
            float rr;
            if (j == 0)      rr = rr0;
            else if (j == 1) rr = rr1;
            else rr = r1[(long long)__shfl(idxv, k, 64)*HC + o];
            int ks = k - (k > 13 ? 1 : 0);
            const u32* wpr = wr + ks*512 + h*256 + o;
            #pragma unroll
            for (int cc2 = 0; cc2 < 8; ++cc2) {
                u32 wv = wpr[cc2*32];
                float xv0 = __shfl(rr, h*16 + 2*cc2, 64);
                float xv1 = __shfl(rr, h*16 + 2*cc2 + 1, 64);
                acc = fmaf(u2f(wv << 16), xv0, acc);
                acc = fmaf(u2f(wv & 0xffff0000u), xv1, acc);
            }
            ++j;
        }
        acc += __shfl_xor(acc, 32, 64);
        float cx2 = fmaxf(acc + brv, 0.f) + 2.f*cvv;
        if (lane < HC) a2_bf[(int)(n - p0)*72 + o] = f2bf(cx2);
    }
    if (p0 >= N) return;

    // epilogue (MFMA)
    bf16x8 bq[2];
    #pragma unroll
    for (int no = 0; no < 2; ++no)
      #pragma unroll
      for (int j = 0; j < 8; ++j)
        bq[no][j] = bfs(Wq3[(g*8+j)*32 + no*16 + m]);
    bf16x8 bgw[4][2];
    #pragma unroll
    for (int no = 0; no < 4; ++no)
      #pragma unroll
      for (int kf = 0; kf < 2; ++kf)
        #pragma unroll
        for (int j = 0; j < 8; ++j)
          bgw[no][kf][j] = bfs(Wg2[(kf*32 + g*8 + j)*64 + no*16 + m]);
    const float bq3a = bq3[m], bq3b = bq3[16+m];
    float bgb[4];
    #pragma unroll
    for (int no = 0; no < 4; ++no) bgb[no] = bg2[no*16 + m];
    const float invNP = (float)(*bsz) / (float)N;
    const int p_lin = lane >> 2, c0 = (lane & 3) * 8;

    {
        long long pp = p0 + p_lin; if (pp > N-1) pp = N-1;
        float m1v = m1[pp];
        int b = batch_id[pp];
        const float4* bsp = (const float4*)(bsum + b*32 + c0);
        float4 bs0 = bsp[0], bs1 = bsp[1];
        const float4* s12p = (const float4*)(s12 + pp*32 + c0);
        float4 s0 = s12p[0], s1 = s12p[1];
        float bsv[8] = {bs0.x,bs0.y,bs0.z,bs0.w,bs1.x,bs1.y,bs1.z,bs1.w};
        float sv[8]  = {s0.x,s0.y,s0.z,s0.w,s1.x,s1.y,s1.z,s1.w};
        bf16x8 fbv;
        #pragma unroll
        for (int j = 0; j < 8; ++j) {
            float enc = sqrtf(m1v * bsv[j] * invNP + 1e-12f);
            fbv[j] = bfs(enc + sv[j]);
        }
        *(bf16x8*)&fin_bf[p_lin*40 + c0] = fbv;
    }
    asm volatile("s_waitcnt lgkmcnt(0)" ::: "memory");
    bf16x8 af = *(const bf16x8*)&fin_bf[m*40 + g*8];
    f32x4 f0 = {0.f,0.f,0.f,0.f}, f1 = {0.f,0.f,0.f,0.f};
    f0 = __builtin_amdgcn_mfma_f32_16x16x32_bf16(af, bq[0], f0, 0,0,0);
    f1 = __builtin_amdgcn_mfma_f32_16x16x32_bf16(af, bq[1], f1, 0,0,0);
    #pragma unroll
    for (int j = 0; j < 4; ++j) {
        int row = g*4 + j;
        long long pr = p0 + row; if (pr > N-1) pr = N-1;
        float fa = fmaxf(f0[j] + bq3a, 0.f);
        float fb = fmaxf(f1[j] + bq3b, 0.f);
        float g0 = fmaxf(gl[pr*32 + m] - fa, 0.f);
        float g1 = fmaxf(gl[pr*32 + 16 + m] - fb, 0.f);
        a2_bf[row*72 + 32 + m] = f2bf(g0);
        a2_bf[row*72 + 48 + m] = f2bf(g1);
    }
    asm volatile("s_waitcnt lgkmcnt(0)" ::: "memory");
    bf16x8 a20 = *(const bf16x8*)&a2_bf[m*72 + g*8];
    bf16x8 a21 = *(const bf16x8*)&a2_bf[m*72 + 32 + g*8];
    #pragma unroll
    for (int no = 0; no < 4; ++no) {
        f32x4 acc = {0.f,0.f,0.f,0.f};
        acc = __builtin_amdgcn_mfma_f32_16x16x32_bf16(a20, bgw[no][0], acc, 0,0,0);
        acc = __builtin_amdgcn_mfma_f32_16x16x32_bf16(a21, bgw[no][1], acc, 0,0,0);
        #pragma unroll
        for (int j = 0; j < 4; ++j) {
            long long pr = p0 + g*4 + j;
            if (pr < N)
                out[pr*64 + no*16 + m] = x[pr*64 + no*16 + m] + acc[j] + bgb[no];
        }
    }
}

extern "C" void kernel_launch(void* const* d_in, const int* in_sizes, int n_in,
                              void* d_out, int out_size, void* d_ws, size_t ws_size,
                              hipStream_t stream) {
    const float* x   = (const float*)d_in[0];
    const float* Wg1 = (const float*)d_in[1];
    const float* bg1 = (const float*)d_in[2];
    const float* Wg2 = (const float*)d_in[3];
    const float* bg2 = (const float*)d_in[4];
    const float* Wr1 = (const float*)d_in[5];
    const float* br1 = (const float*)d_in[6];
    const float* Wr2 = (const float*)d_in[7];
    const float* br2 = (const float*)d_in[8];
    const float* Wq1 = (const float*)d_in[9];
    const float* bq1 = (const float*)d_in[10];
    const float* Wq2 = (const float*)d_in[11];
    const float* bq2 = (const float*)d_in[12];
    const float* Wq3 = (const float*)d_in[13];
    const float* bq3 = (const float*)d_in[14];
    const int* nbr   = (const int*)d_in[15];
    const int* bid   = (const int*)d_in[16];
    const int* bsz   = (const int*)d_in[17];

    const long long N = (long long)in_sizes[0] / 64;

    float* cv   = (float*)d_ws;
    float* gl   = cv  + N * 32;
    float* r1   = gl  + N * 32;
    float* s12  = r1  + N * 32;
    float* m1   = s12 + N * 32;
    float* bsum = m1  + N;               // 128 floats used

    float* out = (float*)d_out;

    hipMemsetAsync(bsum, 0, 128 * sizeof(float), stream);

    long long tiles = (N + 15) / 16;
    long long gwaves = (tiles + 3) / 4;
    int gblocks = (int)((gwaves + 3) / 4);
    k1_mfma<<<gblocks, 256, 0, stream>>>(x, Wg1, bg1, cv, gl, N);

    long long cwaves = (N + CPT - 1) / CPT;
    int blk16 = (int)((cwaves + 15) / 16);
    int blk8  = (int)((cwaves + 7) / 8);
    k2_fused<<<blk16, 1024, 0, stream>>>(cv, gl, nbr, bid, Wr1, br1, Wq1, bq1, Wq2, bq2,
                                         r1, s12, m1, bsum, N);
    k3_fused<<<blk8, 512, 0, stream>>>(r1, cv, gl, s12, m1, bsum, nbr, bid,
                                       Wr2, br2, Wq3, bq3, Wg2, bg2, x, out, N, bsz);
}

// Round 11
// 361.888 us; speedup vs baseline: 2.5312x; 2.5312x over previous
//
#include <hip/hip_runtime.h>
#include <stdint.h>

typedef unsigned int u32;
typedef unsigned short u16;
typedef unsigned long long u64;
typedef __attribute__((ext_vector_type(8))) short bf16x8;
typedef __attribute__((ext_vector_type(4))) float f32x4;

#define HC 32
#define CPT 16

__device__ __forceinline__ float u2f(u32 u){ union{u32 i;float f;}v; v.i=u; return v.f; }
__device__ __forceinline__ u16 f2bf(float f){ union{float f;u32 i;}v; v.f=f; u32 i=v.i;
    return (u16)((i + 0x7FFFu + ((i>>16)&1u))>>16); }  // RNE
__device__ __forceinline__ short bfs(float f){ return (short)f2bf(f); }
__device__ __forceinline__ u32 packbf(float a, float b){ return (u32)f2bf(a) | ((u32)f2bf(b)<<16); }

// stage 26 sparse k-slices (skip k=13), bf16x2 c-pairs
__device__ __forceinline__ void stage_w26(const float* __restrict__ W, u32* __restrict__ wl, int nthr) {
    for (int i = threadIdx.x; i < 26*512; i += nthr) {
        int o = i & 31, row = (i >> 5) & 15, kp = i >> 9;
        int k = kp + (kp >= 13 ? 1 : 0);
        int c0 = (row >> 3)*16 + (row & 7)*2;
        wl[i] = packbf(W[k*1024 + c0*32 + o], W[k*1024 + (c0+1)*32 + o]);
    }
}

// ---- K1: y = x @ Wg1 + bg1 -> cv | gl  (MFMA) ----
__global__ __launch_bounds__(256) void k1_mfma(
    const float* __restrict__ x, const float* __restrict__ Wg1, const float* __restrict__ bg1,
    float* __restrict__ cv, float* __restrict__ gl, long long N)
{
    const int lane = threadIdx.x & 63;
    const int m = lane & 15, g = lane >> 4;
    bf16x8 bw[4][2];
    #pragma unroll
    for (int no = 0; no < 4; ++no)
      #pragma unroll
      for (int kf = 0; kf < 2; ++kf)
        #pragma unroll
        for (int j = 0; j < 8; ++j)
            bw[no][kf][j] = bfs(Wg1[(kf*32 + g*8 + j)*64 + no*16 + m]);
    float bias4[4];
    #pragma unroll
    for (int no = 0; no < 4; ++no) bias4[no] = bg1[no*16 + m];

    const long long wave = (long long)blockIdx.x*4 + (threadIdx.x>>6);
    long long t0 = wave * 4;
    #pragma unroll 1
    for (long long t = t0; t < t0+4; ++t) {
        long long p0 = t*16;
        if (p0 >= N) break;
        long long pr_a = p0 + m; if (pr_a > N-1) pr_a = N-1;
        const float4* xr = (const float4*)(x + pr_a*64);
        bf16x8 aw[2];
        #pragma unroll
        for (int kf = 0; kf < 2; ++kf) {
            float4 lo = xr[kf*8 + g*2];
            float4 hi = xr[kf*8 + g*2 + 1];
            aw[kf][0]=bfs(lo.x); aw[kf][1]=bfs(lo.y); aw[kf][2]=bfs(lo.z); aw[kf][3]=bfs(lo.w);
            aw[kf][4]=bfs(hi.x); aw[kf][5]=bfs(hi.y); aw[kf][6]=bfs(hi.z); aw[kf][7]=bfs(hi.w);
        }
        #pragma unroll
        for (int no = 0; no < 4; ++no) {
            f32x4 acc = {0.f,0.f,0.f,0.f};
            acc = __builtin_amdgcn_mfma_f32_16x16x32_bf16(aw[0], bw[no][0], acc, 0,0,0);
            acc = __builtin_amdgcn_mfma_f32_16x16x32_bf16(aw[1], bw[no][1], acc, 0,0,0);
            #pragma unroll
            for (int j = 0; j < 4; ++j) {
                long long pr = p0 + g*4 + j;
                if (pr < N) {
                    float v = acc[j] + bias4[no];
                    if (no < 2) cv[pr*32 + no*16 + m] = v;
                    else        gl[pr*32 + (no-2)*16 + m] = v;
                }
            }
        }
    }
}

// ---- K2a: r1 = relu(sconv(cv, Wr1) + br1) ; 2-deep gather pipeline (round-9 proven) ----
__global__ __launch_bounds__(512, 4) void k2a_conv(
    const float* __restrict__ cv, const int* __restrict__ nbr,
    const float* __restrict__ Wr1, const float* __restrict__ br1,
    float* __restrict__ r1, long long N)
{
    __shared__ u32 wr[26*512];
    stage_w26(Wr1, wr, 512);
    __syncthreads();
    const int lane = threadIdx.x & 63, o = lane & 31, h = lane >> 5;
    const bool idxlane = (lane < 27 && lane != 13);
    u32 wsr[8];
    #pragma unroll
    for (int cc2 = 0; cc2 < 8; ++cc2)
        wsr[cc2] = packbf(Wr1[13*1024 + (h*16+2*cc2)*32 + o], Wr1[13*1024 + (h*16+2*cc2+1)*32 + o]);
    const float brv = br1[o];

    const long long wave = (long long)blockIdx.x*8 + (threadIdx.x>>6);
    long long n0 = wave*CPT, n1 = n0+CPT; if (n1 > N) n1 = N;
    if (n0 >= n1) return;

    int ia = idxlane ? nbr[(long long)lane*N + n0] : -1;
    int ib = (n0+1 < n1 && idxlane) ? nbr[(long long)lane*N + n0+1] : -1;
    u64 ma = __ballot(ia >= 0);
    float sa = cv[n0*HC + o];
    float ra0 = 0.f, ra1 = 0.f;
    if (ma) {
        int k0 = (int)__builtin_ctzll(ma);
        ra0 = cv[(long long)__shfl(ia, k0, 64)*HC + o];
        u64 m2 = ma & (ma-1);
        if (m2) ra1 = cv[(long long)__shfl(ia, (int)__builtin_ctzll(m2), 64)*HC + o];
    }

    for (long long n = n0; n < n1; ++n) {
        u64 mb = 0; float rb0 = 0.f, rb1 = 0.f, sb = 0.f; int ic = -1;
        if (n+1 < n1) {
            mb = __ballot(ib >= 0);
            sb = cv[(n+1)*HC + o];
            if (mb) {
                int k0 = (int)__builtin_ctzll(mb);
                rb0 = cv[(long long)__shfl(ib, k0, 64)*HC + o];
                u64 m2 = mb & (mb-1);
                if (m2) rb1 = cv[(long long)__shfl(ib, (int)__builtin_ctzll(m2), 64)*HC + o];
            }
            if (n+2 < n1) ic = idxlane ? nbr[(long long)lane*N + n+2] : -1;
        }
        float accr = 0.f;
        #pragma unroll
        for (int cc2 = 0; cc2 < 8; ++cc2) {
            u32 wv = wsr[cc2];
            float xv0 = __shfl(sa, h*16 + 2*cc2, 64);
            float xv1 = __shfl(sa, h*16 + 2*cc2 + 1, 64);
            accr = fmaf(u2f(wv << 16), xv0, accr);
            accr = fmaf(u2f(wv & 0xffff0000u), xv1, accr);
        }
        u64 mm = ma; int j = 0;
        while (mm) {
            int k = (int)__builtin_ctzll(mm); mm &= mm-1;
            float rr;
            if (j == 0)      rr = ra0;
            else if (j == 1) rr = ra1;
            else rr = cv[(long long)__shfl(ia, k, 64)*HC + o];
            int ks = k - (k > 13 ? 1 : 0);
            const u32* wpr = wr + ks*512 + h*256 + o;
            #pragma unroll
            for (int cc2 = 0; cc2 < 8; ++cc2) {
                u32 wv = wpr[cc2*32];
                float xv0 = __shfl(rr, h*16 + 2*cc2, 64);
                float xv1 = __shfl(rr, h*16 + 2*cc2 + 1, 64);
                accr = fmaf(u2f(wv << 16), xv0, accr);
                accr = fmaf(u2f(wv & 0xffff0000u), xv1, accr);
            }
            ++j;
        }
        accr += __shfl_xor(accr, 32, 64);
        if (lane < HC) r1[n*HC + o] = fmaxf(accr + brv, 0.f);
        ia = ib; ib = ic; ma = mb; ra0 = rb0; ra1 = rb1; sa = sb;
    }
}

// ---- K2b: MFMA tile conv for the two q-convs ----
// one wave per 16-point tile: enumerate valid (k,p) pairs, batch-gather rows into
// a compacted A buffer (<=10 k-slices per pass), then 4 MFMAs per active slice.
#define KA 10
__global__ __launch_bounds__(256, 1) void k2b_mfma(
    const float* __restrict__ gl, const int* __restrict__ nbr,
    const int* __restrict__ batch_id,
    const float* __restrict__ Wq1, const float* __restrict__ bq1,
    const float* __restrict__ Wq2, const float* __restrict__ bq2,
    float* __restrict__ s12, float* __restrict__ m1, float* __restrict__ bsum,
    long long N)
{
    __shared__ __align__(16) u16 wfrag[108*512];     // [mat*54+k*2+oh][lane*8] B-frags
    __shared__ __align__(16) u16 Acmp[4][16*328];    // per-wave A: 16 rows x (10 slices*32 + 8 pad)
    __shared__ u16 plist_s[4][224];
    __shared__ int ilist_s[4][224];
    __shared__ u16 slist_s[4][32];
    __shared__ u16 sstart_s[4][32];
    __shared__ float lbs[128];

    // stage B-fragments: wfrag[slot][l][j] = W[k][(l>>4)*8+j][oh*16+(l&15)]
    for (int it = threadIdx.x; it < 6912; it += 256) {
        int l = it & 63, slot = it >> 6;
        int oh = slot & 1, k = (slot >> 1) % 27, mat = slot / 54;
        const float* W = mat ? Wq2 : Wq1;
        const float* src = W + k*1024 + oh*16 + (l & 15);
        int crow = (l >> 4) * 8;
        u32 w4[4];
        #pragma unroll
        for (int jj = 0; jj < 4; ++jj)
            w4[jj] = packbf(src[(crow + 2*jj)*32], src[(crow + 2*jj + 1)*32]);
        *(uint4*)&wfrag[slot*512 + l*8] = make_uint4(w4[0], w4[1], w4[2], w4[3]);
    }
    if (threadIdx.x < 128) lbs[threadIdx.x] = 0.f;
    __syncthreads();

    const int wid = threadIdx.x >> 6;
    const int lane = threadIdx.x & 63;
    const int m = lane & 15, g = lane >> 4;
    const int c32 = lane & 31, hf = lane >> 5;
    u16* A = Acmp[wid];
    u16* plist = plist_s[wid];
    int* ilist = ilist_s[wid];
    u16* slist = slist_s[wid];
    u16* sstart = sstart_s[wid];

    const float b1a = bq1[m], b1b = bq1[16+m], b2a = bq2[m], b2b = bq2[16+m];

    const long long ntiles = (N + 15) >> 4;
    for (long long t = (long long)blockIdx.x*4 + wid; t < ntiles; t += (long long)gridDim.x*4) {
        const long long p0 = t*16;
        // ---- enumerate valid (k,p) pairs, build compacted lists ----
        u32 np = 0, ns = 0;
        #pragma unroll
        for (int ch = 0; ch < 7; ++ch) {
            int i = ch*64 + lane;
            int kk = i >> 4, pp = i & 15;
            int ixv = -1;
            if (i < 432 && p0 + pp < N) ixv = nbr[(long long)kk*N + p0 + pp];
            u64 b = __ballot(ixv >= 0);
            u32 kact = 0;
            #pragma unroll
            for (int q2 = 0; q2 < 4; ++q2)
                kact |= ((((b >> (16*q2)) & 0xffffull) != 0ull) ? 1u : 0u) << q2;
            if (ixv >= 0) {
                u64 ltm = (1ull << lane) - 1ull;
                u32 pos = np + (u32)__popcll(b & ltm);
                int q2 = lane >> 4;
                u32 s = ns + __popc(kact & ((1u << q2) - 1u));
                if (pos < 224) {
                    plist[pos] = (u16)((s << 9) | (u32)pp);
                    ilist[pos] = ixv;
                    u64 subm = 0xffffull << (16*q2);
                    if ((b & subm & ltm) == 0ull) { slist[s] = (u16)kk; sstart[s] = (u16)pos; }
                }
            }
            np += (u32)__popcll(b);
            ns += __popc(kact);
        }
        if (np > 224) np = 224;

        f32x4 acc10 = {0.f,0.f,0.f,0.f}, acc11 = {0.f,0.f,0.f,0.f};
        f32x4 acc20 = {0.f,0.f,0.f,0.f}, acc21 = {0.f,0.f,0.f,0.f};
        asm volatile("s_waitcnt lgkmcnt(0)" ::: "memory");   // lists visible wave-wide

        for (u32 base = 0; base < ns; base += KA) {
            u32 sEnd = base + KA; if (sEnd > ns) sEnd = ns;
            u32 jS = sstart[base];
            u32 jE = (sEnd < ns) ? (u32)sstart[sEnd] : np;
            // clear A slice region [16][0..320)
            uint4 z4 = make_uint4(0u,0u,0u,0u);
            #pragma unroll
            for (int w = 0; w < 10; ++w) {
                int q = w*64 + lane;
                int r = q / 40, c8 = q - r*40;
                *(uint4*)&A[r*328 + c8*8] = z4;
            }
            asm volatile("s_waitcnt lgkmcnt(0)" ::: "memory");
            // fill: 16 pairs per chunk (2 pairs per load slot, half-wave each)
            for (u32 j0 = jS; j0 < jE; j0 += 16) {
                float v[8]; u32 mt[8];
                #pragma unroll
                for (int tt = 0; tt < 8; ++tt) {
                    u32 pj = j0 + 2*tt + (u32)hf;
                    bool val = pj < jE;
                    u32 pm = val ? (u32)plist[pj] : 0u;
                    int ix = val ? ilist[pj] : 0;
                    mt[tt] = val ? (pm | 0x80000000u) : 0u;
                    v[tt] = val ? gl[(long long)ix*32 + c32] : 0.f;
                }
                #pragma unroll
                for (int tt = 0; tt < 8; ++tt) {
                    if (mt[tt] >> 31) {
                        u32 sl = ((mt[tt] >> 9) & 31u) - base;
                        u32 p = mt[tt] & 15u;
                        A[p*328 + sl*32 + c32] = f2bf(v[tt]);
                    }
                }
            }
            asm volatile("s_waitcnt lgkmcnt(0)" ::: "memory");
            // MFMA per active slice: out += A_k @ Wq{1,2}[k]
            for (u32 s = base; s < sEnd; ++s) {
                int sl = (int)(s - base);
                int k = slist[s];
                bf16x8 af  = *(const bf16x8*)&A[m*328 + sl*32 + g*8];
                bf16x8 w10 = *(const bf16x8*)&wfrag[(k*2 + 0)*512 + lane*8];
                bf16x8 w11 = *(const bf16x8*)&wfrag[(k*2 + 1)*512 + lane*8];
                bf16x8 w20 = *(const bf16x8*)&wfrag[(54 + k*2 + 0)*512 + lane*8];
                bf16x8 w21 = *(const bf16x8*)&wfrag[(54 + k*2 + 1)*512 + lane*8];
                acc10 = __builtin_amdgcn_mfma_f32_16x16x32_bf16(af, w10, acc10, 0,0,0);
                acc11 = __builtin_amdgcn_mfma_f32_16x16x32_bf16(af, w11, acc11, 0,0,0);
                acc20 = __builtin_amdgcn_mfma_f32_16x16x32_bf16(af, w20, acc20, 0,0,0);
                acc21 = __builtin_amdgcn_mfma_f32_16x16x32_bf16(af, w21, acc21, 0,0,0);
            }
        }
        // ---- epilogue: bias+relu, s12, m1, batch sums ----
        #pragma unroll
        for (int j = 0; j < 4; ++j) {
            long long pr = p0 + g*4 + j;
            if (pr < N) {
                float o1a = fmaxf(acc10[j] + b1a, 0.f);
                float o1b = fmaxf(acc11[j] + b1b, 0.f);
                float o2a = fmaxf(acc20[j] + b2a, 0.f);
                float o2b = fmaxf(acc21[j] + b2b, 0.f);
                s12[pr*32 + m]      = o1a + o2a;
                s12[pr*32 + 16 + m] = o1b + o2b;
                float rs = o1a + o1b;
                #pragma unroll
                for (int d = 1; d < 16; d <<= 1) rs += __shfl_xor(rs, d, 64);
                if (m == 0) m1[pr] = rs * (1.f/32.f);
                int bb = batch_id[pr];
                atomicAdd(&lbs[bb*32 + m], o2a);
                atomicAdd(&lbs[bb*32 + 16 + m], o2b);
            }
        }
    }
    __syncthreads();
    if (threadIdx.x < 128) atomicAdd(&bsum[threadIdx.x], lbs[threadIdx.x]);
}

// ---- K3 fused: r2-conv -> cx2 tile in LDS -> MFMA epilogue -> out (round-9 proven) ----
__global__ __launch_bounds__(512, 1) void k3_fused(
    const float* __restrict__ r1, const float* __restrict__ cv,
    const float* __restrict__ gl, const float* __restrict__ s12,
    const float* __restrict__ m1, const float* __restrict__ bsum,
    const int* __restrict__ nbr, const int* __restrict__ batch_id,
    const float* __restrict__ Wr2, const float* __restrict__ br2,
    const float* __restrict__ Wq3, const float* __restrict__ bq3,
    const float* __restrict__ Wg2, const float* __restrict__ bg2,
    const float* __restrict__ x, float* __restrict__ out,
    long long N, const int* __restrict__ bsz)
{
    __shared__ u32 wr[26*512];
    __shared__ __align__(16) u16 finL[8][16*40];
    __shared__ __align__(16) u16 a2L[8][16*72];
    stage_w26(Wr2, wr, 512);
    __syncthreads();

    const int wid = threadIdx.x >> 6;
    u16* fin_bf = finL[wid];
    u16* a2_bf  = a2L[wid];
    const int lane = threadIdx.x & 63, o = lane & 31, h = lane >> 5;
    const int m = lane & 15, g = lane >> 4;
    const bool idxlane = (lane < 27 && lane != 13);

    u32 wsr[8];
    #pragma unroll
    for (int cc2 = 0; cc2 < 8; ++cc2)
        wsr[cc2] = packbf(Wr2[13*1024 + (h*16+2*cc2)*32 + o], Wr2[13*1024 + (h*16+2*cc2+1)*32 + o]);
    const float brv = br2[o];

    const long long wave = (long long)blockIdx.x*8 + wid;
    const long long p0 = wave*CPT;
    long long n0 = p0, n1 = n0+CPT; if (n1 > N) n1 = N;

    int cidx = -1; float pself = 0.f, pcv = 0.f;
    if (n0 < n1) {
        cidx = idxlane ? nbr[(long long)lane*N + n0] : -1;
        pself = r1[n0*HC + o]; pcv = cv[n0*HC + o];
    }
    for (long long n = n0; n < n1; ++n) {
        int idxv = cidx;
        float selfv = pself, cvv = pcv;
        u32 mask = (u32)__ballot(idxv >= 0);
        float rr0=0.f, rr1=0.f;
        if (mask) {
            int k0 = (int)__builtin_ctz(mask);
            rr0 = r1[(long long)__shfl(idxv, k0, 64)*HC + o];
            u32 m2 = mask & (mask-1);
            if (m2) rr1 = r1[(long long)__shfl(idxv, (int)__builtin_ctz(m2), 64)*HC + o];
        }
        if (n+1 < n1) {
            cidx = idxlane ? nbr[(long long)lane*N + n+1] : -1;
            pself = r1[(n+1)*HC + o]; pcv = cv[(n+1)*HC + o];
        }
        float acc = 0.f;
        #pragma unroll
        for (int cc2 = 0; cc2 < 8; ++cc2) {
            u32 wv = wsr[cc2];
            float xv0 = __shfl(selfv, h*16 + 2*cc2, 64);
            float xv1 = __shfl(selfv, h*16 + 2*cc2 + 1, 64);
            acc = fmaf(u2f(wv << 16), xv0, acc);
            acc = fmaf(u2f(wv & 0xffff0000u), xv1, acc);
        }
        u32 mm = mask; int j = 0;
        while (mm) {
            int k = (int)__builtin_ctz(mm); mm &= mm-1;
            float rr;
            if (j == 0)      rr = rr0;
            else if (j == 1) rr = rr1;
            else rr = r1[(long long)__shfl(idxv, k, 64)*HC + o];
            int ks = k - (k > 13 ? 1 : 0);
            const u32* wpr = wr + ks*512 + h*256 + o;
            #pragma unroll
            for (int cc2 = 0; cc2 < 8; ++cc2) {
                u32 wv = wpr[cc2*32];
                float xv0 = __shfl(rr, h*16 + 2*cc2, 64);
                float xv1 = __shfl(rr, h*16 + 2*cc2 + 1, 64);
                acc = fmaf(u2f(wv << 16), xv0, acc);
                acc = fmaf(u2f(wv & 0xffff0000u), xv1, acc);
            }
            ++j;
        }
        acc += __shfl_xor(acc, 32, 64);
        float cx2 = fmaxf(acc + brv, 0.f) + 2.f*cvv;
        if (lane < HC) a2_bf[(int)(n - p0)*72 + o] = f2bf(cx2);
    }
    if (p0 >= N) return;

    bf16x8 bq[2];
    #pragma unroll
    for (int no = 0; no < 2; ++no)
      #pragma unroll
      for (int j = 0; j < 8; ++j)
        bq[no][j] = bfs(Wq3[(g*8+j)*32 + no*16 + m]);
    bf16x8 bgw[4][2];
    #pragma unroll
    for (int no = 0; no < 4; ++no)
      #pragma unroll
      for (int kf = 0; kf < 2; ++kf)
        #pragma unroll
        for (int j = 0; j < 8; ++j)
          bgw[no][kf][j] = bfs(Wg2[(kf*32 + g*8 + j)*64 + no*16 + m]);
    const float bq3a = bq3[m], bq3b = bq3[16+m];
    float bgb[4];
    #pragma unroll
    for (int no = 0; no < 4; ++no) bgb[no] = bg2[no*16 + m];
    const float invNP = (float)(*bsz) / (float)N;
    const int p_lin = lane >> 2, c0 = (lane & 3) * 8;

    {
        long long pp = p0 + p_lin; if (pp > N-1) pp = N-1;
        float m1v = m1[pp];
        int b = batch_id[pp];
        const float4* bsp = (const float4*)(bsum + b*32 + c0);
        float4 bs0 = bsp[0], bs1 = bsp[1];
        const float4* s12p = (const float4*)(s12 + pp*32 + c0);
        float4 s0 = s12p[0], s1 = s12p[1];
        float bsv[8] = {bs0.x,bs0.y,bs0.z,bs0.w,bs1.x,bs1.y,bs1.z,bs1.w};
        float sv[8]  = {s0.x,s0.y,s0.z,s0.w,s1.x,s1.y,s1.z,s1.w};
        bf16x8 fbv;
        #pragma unroll
        for (int j = 0; j < 8; ++j) {
            float enc = sqrtf(m1v * bsv[j] * invNP + 1e-12f);
            fbv[j] = bfs(enc + sv[j]);
        }
        *(bf16x8*)&fin_bf[p_lin*40 + c0] = fbv;
    }
    asm volatile("s_waitcnt lgkmcnt(0)" ::: "memory");
    bf16x8 af = *(const bf16x8*)&fin_bf[m*40 + g*8];
    f32x4 f0 = {0.f,0.f,0.f,0.f}, f1 = {0.f,0.f,0.f,0.f};
    f0 = __builtin_amdgcn_mfma_f32_16x16x32_bf16(af, bq[0], f0, 0,0,0);
    f1 = __builtin_amdgcn_mfma_f32_16x16x32_bf16(af, bq[1], f1, 0,0,0);
    #pragma unroll
    for (int j = 0; j < 4; ++j) {
        int row = g*4 + j;
        long long pr = p0 + row; if (pr > N-1) pr = N-1;
        float fa = fmaxf(f0[j] + bq3a, 0.f);
        float fb = fmaxf(f1[j] + bq3b, 0.f);
        float g0 = fmaxf(gl[pr*32 + m] - fa, 0.f);
        float g1 = fmaxf(gl[pr*32 + 16 + m] - fb, 0.f);
        a2_bf[row*72 + 32 + m] = f2bf(g0);
        a2_bf[row*72 + 48 + m] = f2bf(g1);
    }
    asm volatile("s_waitcnt lgkmcnt(0)" ::: "memory");
    bf16x8 a20 = *(const bf16x8*)&a2_bf[m*72 + g*8];
    bf16x8 a21 = *(const bf16x8*)&a2_bf[m*72 + 32 + g*8];
    #pragma unroll
    for (int no = 0; no < 4; ++no) {
        f32x4 acc = {0.f,0.f,0.f,0.f};
        acc = __builtin_amdgcn_mfma_f32_16x16x32_bf16(a20, bgw[no][0], acc, 0,0,0);
        acc = __builtin_amdgcn_mfma_f32_16x16x32_bf16(a21, bgw[no][1], acc, 0,0,0);
        #pragma unroll
        for (int j = 0; j < 4; ++j) {
            long long pr = p0 + g*4 + j;
            if (pr < N)
                out[pr*64 + no*16 + m] = x[pr*64 + no*16 + m] + acc[j] + bgb[no];
        }
    }
}

extern "C" void kernel_launch(void* const* d_in, const int* in_sizes, int n_in,
                              void* d_out, int out_size, void* d_ws, size_t ws_size,
                              hipStream_t stream) {
    const float* x   = (const float*)d_in[0];
    const float* Wg1 = (const float*)d_in[1];
    const float* bg1 = (const float*)d_in[2];
    const float* Wg2 = (const float*)d_in[3];
    const float* bg2 = (const float*)d_in[4];
    const float* Wr1 = (const float*)d_in[5];
    const float* br1 = (const float*)d_in[6];
    const float* Wr2 = (const float*)d_in[7];
    const float* br2 = (const float*)d_in[8];
    const float* Wq1 = (const float*)d_in[9];
    const float* bq1 = (const float*)d_in[10];
    const float* Wq2 = (const float*)d_in[11];
    const float* bq2 = (const float*)d_in[12];
    const float* Wq3 = (const float*)d_in[13];
    const float* bq3 = (const float*)d_in[14];
    const int* nbr   = (const int*)d_in[15];
    const int* bid   = (const int*)d_in[16];
    const int* bsz   = (const int*)d_in[17];

    const long long N = (long long)in_sizes[0] / 64;

    float* cv   = (float*)d_ws;
    float* gl   = cv  + N * 32;
    float* r1   = gl  + N * 32;
    float* s12  = r1  + N * 32;
    float* m1   = s12 + N * 32;
    float* bsum = m1  + N;               // 128 floats used

    float* out = (float*)d_out;

    hipMemsetAsync(bsum, 0, 128 * sizeof(float), stream);

    long long tiles = (N + 15) / 16;
    long long gwaves = (tiles + 3) / 4;
    int gblocks = (int)((gwaves + 3) / 4);
    k1_mfma<<<gblocks, 256, 0, stream>>>(x, Wg1, bg1, cv, gl, N);

    long long cwaves = (N + CPT - 1) / CPT;
    int blk8 = (int)((cwaves + 7) / 8);
    k2a_conv<<<blk8, 512, 0, stream>>>(cv, nbr, Wr1, br1, r1, N);
    k2b_mfma<<<256, 256, 0, stream>>>(gl, nbr, bid, Wq1, bq1, Wq2, bq2, s12, m1, bsum, N);
    k3_fused<<<blk8, 512, 0, stream>>>(r1, cv, gl, s12, m1, bsum, nbr, bid,
                                       Wr2, br2, Wq3, bq3, Wg2, bg2, x, out, N, bsz);
}

// Round 12
// 318.157 us; speedup vs baseline: 2.8791x; 1.1374x over previous
//
#include <hip/hip_runtime.h>
#include <stdint.h>

typedef unsigned int u32;
typedef unsigned short u16;
typedef unsigned long long u64;
typedef __attribute__((ext_vector_type(8))) short bf16x8;
typedef __attribute__((ext_vector_type(4))) float f32x4;

#define HC 32
#define CPT 16

__device__ __forceinline__ float u2f(u32 u){ union{u32 i;float f;}v; v.i=u; return v.f; }
__device__ __forceinline__ u16 f2bf(float f){ union{float f;u32 i;}v; v.f=f; u32 i=v.i;
    return (u16)((i + 0x7FFFu + ((i>>16)&1u))>>16); }  // RNE
__device__ __forceinline__ short bfs(float f){ return (short)f2bf(f); }
__device__ __forceinline__ u32 packbf(float a, float b){ return (u32)f2bf(a) | ((u32)f2bf(b)<<16); }

// stage 26 sparse k-slices (skip k=13), bf16x2 c-pairs
__device__ __forceinline__ void stage_w26(const float* __restrict__ W, u32* __restrict__ wl, int nthr) {
    for (int i = threadIdx.x; i < 26*512; i += nthr) {
        int o = i & 31, row = (i >> 5) & 15, kp = i >> 9;
        int k = kp + (kp >= 13 ? 1 : 0);
        int c0 = (row >> 3)*16 + (row & 7)*2;
        wl[i] = packbf(W[k*1024 + c0*32 + o], W[k*1024 + (c0+1)*32 + o]);
    }
}

// ---- K0: precompute B-fragments of Wq1/Wq2 into global ws (frag layout, bf16) ----
// wsB[slot*512 + l*8 + j] = bf16(W[k][(l>>4)*8 + j][oh*16 + (l&15)]), slot = mat*54 + k*2 + oh
__global__ __launch_bounds__(256) void k0_prep(
    const float* __restrict__ Wq1, const float* __restrict__ Wq2, u16* __restrict__ wsB)
{
    int it = blockIdx.x*256 + threadIdx.x;
    if (it >= 6912) return;
    int l = it & 63, slot = it >> 6;
    int oh = slot & 1, k = (slot >> 1) % 27, mat = slot / 54;
    const float* W = mat ? Wq2 : Wq1;
    const float* src = W + k*1024 + oh*16 + (l & 15);
    int crow = (l >> 4) * 8;
    u32 w4[4];
    #pragma unroll
    for (int jj = 0; jj < 4; ++jj)
        w4[jj] = packbf(src[(crow + 2*jj)*32], src[(crow + 2*jj + 1)*32]);
    *(uint4*)&wsB[slot*512 + l*8] = make_uint4(w4[0], w4[1], w4[2], w4[3]);
}

// ---- K1: y = x @ Wg1 + bg1 -> cv | gl  (MFMA) ----
__global__ __launch_bounds__(256) void k1_mfma(
    const float* __restrict__ x, const float* __restrict__ Wg1, const float* __restrict__ bg1,
    float* __restrict__ cv, float* __restrict__ gl, long long N)
{
    const int lane = threadIdx.x & 63;
    const int m = lane & 15, g = lane >> 4;
    bf16x8 bw[4][2];
    #pragma unroll
    for (int no = 0; no < 4; ++no)
      #pragma unroll
      for (int kf = 0; kf < 2; ++kf)
        #pragma unroll
        for (int j = 0; j < 8; ++j)
            bw[no][kf][j] = bfs(Wg1[(kf*32 + g*8 + j)*64 + no*16 + m]);
    float bias4[4];
    #pragma unroll
    for (int no = 0; no < 4; ++no) bias4[no] = bg1[no*16 + m];

    const long long wave = (long long)blockIdx.x*4 + (threadIdx.x>>6);
    long long t0 = wave * 4;
    #pragma unroll 1
    for (long long t = t0; t < t0+4; ++t) {
        long long p0 = t*16;
        if (p0 >= N) break;
        long long pr_a = p0 + m; if (pr_a > N-1) pr_a = N-1;
        const float4* xr = (const float4*)(x + pr_a*64);
        bf16x8 aw[2];
        #pragma unroll
        for (int kf = 0; kf < 2; ++kf) {
            float4 lo = xr[kf*8 + g*2];
            float4 hi = xr[kf*8 + g*2 + 1];
            aw[kf][0]=bfs(lo.x); aw[kf][1]=bfs(lo.y); aw[kf][2]=bfs(lo.z); aw[kf][3]=bfs(lo.w);
            aw[kf][4]=bfs(hi.x); aw[kf][5]=bfs(hi.y); aw[kf][6]=bfs(hi.z); aw[kf][7]=bfs(hi.w);
        }
        #pragma unroll
        for (int no = 0; no < 4; ++no) {
            f32x4 acc = {0.f,0.f,0.f,0.f};
            acc = __builtin_amdgcn_mfma_f32_16x16x32_bf16(aw[0], bw[no][0], acc, 0,0,0);
            acc = __builtin_amdgcn_mfma_f32_16x16x32_bf16(aw[1], bw[no][1], acc, 0,0,0);
            #pragma unroll
            for (int j = 0; j < 4; ++j) {
                long long pr = p0 + g*4 + j;
                if (pr < N) {
                    float v = acc[j] + bias4[no];
                    if (no < 2) cv[pr*32 + no*16 + m] = v;
                    else        gl[pr*32 + (no-2)*16 + m] = v;
                }
            }
        }
    }
}

// ---- K2a: r1 = relu(sconv(cv, Wr1) + br1) ; 2-deep gather pipeline (round-9 proven) ----
__global__ __launch_bounds__(512, 4) void k2a_conv(
    const float* __restrict__ cv, const int* __restrict__ nbr,
    const float* __restrict__ Wr1, const float* __restrict__ br1,
    float* __restrict__ r1, long long N)
{
    __shared__ u32 wr[26*512];
    stage_w26(Wr1, wr, 512);
    __syncthreads();
    const int lane = threadIdx.x & 63, o = lane & 31, h = lane >> 5;
    const bool idxlane = (lane < 27 && lane != 13);
    u32 wsr[8];
    #pragma unroll
    for (int cc2 = 0; cc2 < 8; ++cc2)
        wsr[cc2] = packbf(Wr1[13*1024 + (h*16+2*cc2)*32 + o], Wr1[13*1024 + (h*16+2*cc2+1)*32 + o]);
    const float brv = br1[o];

    const long long wave = (long long)blockIdx.x*8 + (threadIdx.x>>6);
    long long n0 = wave*CPT, n1 = n0+CPT; if (n1 > N) n1 = N;
    if (n0 >= n1) return;

    int ia = idxlane ? nbr[(long long)lane*N + n0] : -1;
    int ib = (n0+1 < n1 && idxlane) ? nbr[(long long)lane*N + n0+1] : -1;
    u64 ma = __ballot(ia >= 0);
    float sa = cv[n0*HC + o];
    float ra0 = 0.f, ra1 = 0.f;
    if (ma) {
        int k0 = (int)__builtin_ctzll(ma);
        ra0 = cv[(long long)__shfl(ia, k0, 64)*HC + o];
        u64 m2 = ma & (ma-1);
        if (m2) ra1 = cv[(long long)__shfl(ia, (int)__builtin_ctzll(m2), 64)*HC + o];
    }

    for (long long n = n0; n < n1; ++n) {
        u64 mb = 0; float rb0 = 0.f, rb1 = 0.f, sb = 0.f; int ic = -1;
        if (n+1 < n1) {
            mb = __ballot(ib >= 0);
            sb = cv[(n+1)*HC + o];
            if (mb) {
                int k0 = (int)__builtin_ctzll(mb);
                rb0 = cv[(long long)__shfl(ib, k0, 64)*HC + o];
                u64 m2 = mb & (mb-1);
                if (m2) rb1 = cv[(long long)__shfl(ib, (int)__builtin_ctzll(m2), 64)*HC + o];
            }
            if (n+2 < n1) ic = idxlane ? nbr[(long long)lane*N + n+2] : -1;
        }
        float accr = 0.f;
        #pragma unroll
        for (int cc2 = 0; cc2 < 8; ++cc2) {
            u32 wv = wsr[cc2];
            float xv0 = __shfl(sa, h*16 + 2*cc2, 64);
            float xv1 = __shfl(sa, h*16 + 2*cc2 + 1, 64);
            accr = fmaf(u2f(wv << 16), xv0, accr);
            accr = fmaf(u2f(wv & 0xffff0000u), xv1, accr);
        }
        u64 mm = ma; int j = 0;
        while (mm) {
            int k = (int)__builtin_ctzll(mm); mm &= mm-1;
            float rr;
            if (j == 0)      rr = ra0;
            else if (j == 1) rr = ra1;
            else rr = cv[(long long)__shfl(ia, k, 64)*HC + o];
            int ks = k - (k > 13 ? 1 : 0);
            const u32* wpr = wr + ks*512 + h*256 + o;
            #pragma unroll
            for (int cc2 = 0; cc2 < 8; ++cc2) {
                u32 wv = wpr[cc2*32];
                float xv0 = __shfl(rr, h*16 + 2*cc2, 64);
                float xv1 = __shfl(rr, h*16 + 2*cc2 + 1, 64);
                accr = fmaf(u2f(wv << 16), xv0, accr);
                accr = fmaf(u2f(wv & 0xffff0000u), xv1, accr);
            }
            ++j;
        }
        accr += __shfl_xor(accr, 32, 64);
        if (lane < HC) r1[n*HC + o] = fmaxf(accr + brv, 0.f);
        ia = ib; ib = ic; ma = mb; ra0 = rb0; ra1 = rb1; sa = sb;
    }
}

// ---- K2b: MFMA tile conv, B-frags from global (L2-resident) ----
#define KA 10
__global__ __launch_bounds__(256, 1) void k2b_mfma(
    const float* __restrict__ gl, const int* __restrict__ nbr,
    const int* __restrict__ batch_id, const u16* __restrict__ wsB,
    const float* __restrict__ bq1, const float* __restrict__ bq2,
    float* __restrict__ s12, float* __restrict__ m1, float* __restrict__ bsum,
    long long N)
{
    __shared__ __align__(16) u16 Acmp[4][16*328];    // per-wave A: 16 rows x (10 slices*32 + 8 pad)
    __shared__ u16 plist_s[4][224];
    __shared__ int ilist_s[4][224];
    __shared__ u16 slist_s[4][32];
    __shared__ u16 sstart_s[4][32];
    __shared__ float lbs[128];

    if (threadIdx.x < 128) lbs[threadIdx.x] = 0.f;
    __syncthreads();

    const int wid = threadIdx.x >> 6;
    const int lane = threadIdx.x & 63;
    const int m = lane & 15, g = lane >> 4;
    const int c32 = lane & 31, hf = lane >> 5;
    u16* A = Acmp[wid];
    u16* plist = plist_s[wid];
    int* ilist = ilist_s[wid];
    u16* slist = slist_s[wid];
    u16* sstart = sstart_s[wid];

    const float b1a = bq1[m], b1b = bq1[16+m], b2a = bq2[m], b2b = bq2[16+m];

    const long long ntiles = (N + 15) >> 4;
    for (long long t = (long long)blockIdx.x*4 + wid; t < ntiles; t += (long long)gridDim.x*4) {
        const long long p0 = t*16;
        // ---- enumerate valid (k,p) pairs, build compacted lists ----
        u32 np = 0, ns = 0;
        #pragma unroll
        for (int ch = 0; ch < 7; ++ch) {
            int i = ch*64 + lane;
            int kk = i >> 4, pp = i & 15;
            int ixv = -1;
            if (i < 432 && p0 + pp < N) ixv = nbr[(long long)kk*N + p0 + pp];
            u64 b = __ballot(ixv >= 0);
            u32 kact = 0;
            #pragma unroll
            for (int q2 = 0; q2 < 4; ++q2)
                kact |= ((((b >> (16*q2)) & 0xffffull) != 0ull) ? 1u : 0u) << q2;
            if (ixv >= 0) {
                u64 ltm = (1ull << lane) - 1ull;
                u32 pos = np + (u32)__popcll(b & ltm);
                int q2 = lane >> 4;
                u32 s = ns + __popc(kact & ((1u << q2) - 1u));
                if (pos < 224) {
                    plist[pos] = (u16)((s << 9) | (u32)pp);
                    ilist[pos] = ixv;
                    u64 subm = 0xffffull << (16*q2);
                    if ((b & subm & ltm) == 0ull) { slist[s] = (u16)kk; sstart[s] = (u16)pos; }
                }
            }
            np += (u32)__popcll(b);
            ns += __popc(kact);
        }
        if (np > 224) np = 224;

        f32x4 acc10 = {0.f,0.f,0.f,0.f}, acc11 = {0.f,0.f,0.f,0.f};
        f32x4 acc20 = {0.f,0.f,0.f,0.f}, acc21 = {0.f,0.f,0.f,0.f};
        asm volatile("s_waitcnt lgkmcnt(0)" ::: "memory");   // lists visible wave-wide

        for (u32 base = 0; base < ns; base += KA) {
            u32 sEnd = base + KA; if (sEnd > ns) sEnd = ns;
            u32 jS = sstart[base];
            u32 jE = (sEnd < ns) ? (u32)sstart[sEnd] : np;
            // clear A slice region [16][0..320)
            uint4 z4 = make_uint4(0u,0u,0u,0u);
            #pragma unroll
            for (int w = 0; w < 10; ++w) {
                int q = w*64 + lane;
                int r = q / 40, c8 = q - r*40;
                *(uint4*)&A[r*328 + c8*8] = z4;
            }
            asm volatile("s_waitcnt lgkmcnt(0)" ::: "memory");
            // fill: 16 pairs per chunk (2 pairs per load slot, half-wave each)
            for (u32 j0 = jS; j0 < jE; j0 += 16) {
                float v[8]; u32 mt[8];
                #pragma unroll
                for (int tt = 0; tt < 8; ++tt) {
                    u32 pj = j0 + 2*tt + (u32)hf;
                    bool val = pj < jE;
                    u32 pm = val ? (u32)plist[pj] : 0u;
                    int ix = val ? ilist[pj] : 0;
                    mt[tt] = val ? (pm | 0x80000000u) : 0u;
                    v[tt] = val ? gl[(long long)ix*32 + c32] : 0.f;
                }
                #pragma unroll
                for (int tt = 0; tt < 8; ++tt) {
                    if (mt[tt] >> 31) {
                        u32 sl = ((mt[tt] >> 9) & 31u) - base;
                        u32 p = mt[tt] & 15u;
                        A[p*328 + sl*32 + c32] = f2bf(v[tt]);
                    }
                }
            }
            asm volatile("s_waitcnt lgkmcnt(0)" ::: "memory");
            // MFMA per active slice: out += A_k @ Wq{1,2}[k]  (B-frags from global/L2)
            for (u32 s = base; s < sEnd; ++s) {
                int sl = (int)(s - base);
                int k = slist[s];
                bf16x8 af  = *(const bf16x8*)&A[m*328 + sl*32 + g*8];
                bf16x8 w10 = *(const bf16x8*)&wsB[(k*2 + 0)*512 + lane*8];
                bf16x8 w11 = *(const bf16x8*)&wsB[(k*2 + 1)*512 + lane*8];
                bf16x8 w20 = *(const bf16x8*)&wsB[(54 + k*2 + 0)*512 + lane*8];
                bf16x8 w21 = *(const bf16x8*)&wsB[(54 + k*2 + 1)*512 + lane*8];
                acc10 = __builtin_amdgcn_mfma_f32_16x16x32_bf16(af, w10, acc10, 0,0,0);
                acc11 = __builtin_amdgcn_mfma_f32_16x16x32_bf16(af, w11, acc11, 0,0,0);
                acc20 = __builtin_amdgcn_mfma_f32_16x16x32_bf16(af, w20, acc20, 0,0,0);
                acc21 = __builtin_amdgcn_mfma_f32_16x16x32_bf16(af, w21, acc21, 0,0,0);
            }
        }
        // ---- epilogue: bias+relu, s12, m1, batch sums ----
        #pragma unroll
        for (int j = 0; j < 4; ++j) {
            long long pr = p0 + g*4 + j;
            if (pr < N) {
                float o1a = fmaxf(acc10[j] + b1a, 0.f);
                float o1b = fmaxf(acc11[j] + b1b, 0.f);
                float o2a = fmaxf(acc20[j] + b2a, 0.f);
                float o2b = fmaxf(acc21[j] + b2b, 0.f);
                s12[pr*32 + m]      = o1a + o2a;
                s12[pr*32 + 16 + m] = o1b + o2b;
                float rs = o1a + o1b;
                #pragma unroll
                for (int d = 1; d < 16; d <<= 1) rs += __shfl_xor(rs, d, 64);
                if (m == 0) m1[pr] = rs * (1.f/32.f);
                int bb = batch_id[pr];
                atomicAdd(&lbs[bb*32 + m], o2a);
                atomicAdd(&lbs[bb*32 + 16 + m], o2b);
            }
        }
    }
    __syncthreads();
    if (threadIdx.x < 128) atomicAdd(&bsum[threadIdx.x], lbs[threadIdx.x]);
}

// ---- K3 fused: r2-conv -> cx2 tile in LDS -> MFMA epilogue -> out (round-9 proven) ----
__global__ __launch_bounds__(512, 1) void k3_fused(
    const float* __restrict__ r1, const float* __restrict__ cv,
    const float* __restrict__ gl, const float* __restrict__ s12,
    const float* __restrict__ m1, const float* __restrict__ bsum,
    const int* __restrict__ nbr, const int* __restrict__ batch_id,
    const float* __restrict__ Wr2, const float* __restrict__ br2,
    const float* __restrict__ Wq3, const float* __restrict__ bq3,
    const float* __restrict__ Wg2, const float* __restrict__ bg2,
    const float* __restrict__ x, float* __restrict__ out,
    long long N, const int* __restrict__ bsz)
{
    __shared__ u32 wr[26*512];
    __shared__ __align__(16) u16 finL[8][16*40];
    __shared__ __align__(16) u16 a2L[8][16*72];
    stage_w26(Wr2, wr, 512);
    __syncthreads();

    const int wid = threadIdx.x >> 6;
    u16* fin_bf = finL[wid];
    u16* a2_bf  = a2L[wid];
    const int lane = threadIdx.x & 63, o = lane & 31, h = lane >> 5;
    const int m = lane & 15, g = lane >> 4;
    const bool idxlane = (lane < 27 && lane != 13);

    u32 wsr[8];
    #pragma unroll
    for (int cc2 = 0; cc2 < 8; ++cc2)
        wsr[cc2] = packbf(Wr2[13*1024 + (h*16+2*cc2)*32 + o], Wr2[13*1024 + (h*16+2*cc2+1)*32 + o]);
    const float brv = br2[o];

    const long long wave = (long long)blockIdx.x*8 + wid;
    const long long p0 = wave*CPT;
    long long n0 = p0, n1 = n0+CPT; if (n1 > N) n1 = N;

    int cidx = -1; float pself = 0.f, pcv = 0.f;
    if (n0 < n1) {
        cidx = idxlane ? nbr[(long long)lane*N + n0] : -1;
        pself = r1[n0*HC + o]; pcv = cv[n0*HC + o];
    }
    for (long long n = n0; n < n1; ++n) {
        int idxv = cidx;
        float selfv = pself, cvv = pcv;
        u32 mask = (u32)__ballot(idxv >= 0);
        float rr0=0.f, rr1=0.f;
        if (mask) {
            int k0 = (int)__builtin_ctz(mask);
            rr0 = r1[(long long)__shfl(idxv, k0, 64)*HC + o];
            u32 m2 = mask & (mask-1);
            if (m2) rr1 = r1[(long long)__shfl(idxv, (int)__builtin_ctz(m2), 64)*HC + o];
        }
        if (n+1 < n1) {
            cidx = idxlane ? nbr[(long long)lane*N + n+1] : -1;
            pself = r1[(n+1)*HC + o]; pcv = cv[(n+1)*HC + o];
        }
        float acc = 0.f;
        #pragma unroll
        for (int cc2 = 0; cc2 < 8; ++cc2) {
            u32 wv = wsr[cc2];
            float xv0 = __shfl(selfv, h*16 + 2*cc2, 64);
            float xv1 = __shfl(selfv, h*16 + 2*cc2 + 1, 64);
            acc = fmaf(u2f(wv << 16), xv0, acc);
            acc = fmaf(u2f(wv & 0xffff0000u), xv1, acc);
        }
        u32 mm = mask; int j = 0;
        while (mm) {
            int k = (int)__builtin_ctz(mm); mm &= mm-1;
            float rr;
            if (j == 0)      rr = rr0;
            else if (j == 1) rr = rr1;
            else rr = r1[(long long)__shfl(idxv, k, 64)*HC + o];
            int ks = k - (k > 13 ? 1 : 0);
            const u32* wpr = wr + ks*512 + h*256 + o;
            #pragma unroll
            for (int cc2 = 0; cc2 < 8; ++cc2) {
                u32 wv = wpr[cc2*32];
                float xv0 = __shfl(rr, h*16 + 2*cc2, 64);
                float xv1 = __shfl(rr, h*16 + 2*cc2 + 1, 64);
                acc = fmaf(u2f(wv << 16), xv0, acc);
                acc = fmaf(u2f(wv & 0xffff0000u), xv1, acc);
            }
            ++j;
        }
        acc += __shfl_xor(acc, 32, 64);
        float cx2 = fmaxf(acc + brv, 0.f) + 2.f*cvv;
        if (lane < HC) a2_bf[(int)(n - p0)*72 + o] = f2bf(cx2);
    }
    if (p0 >= N) return;

    bf16x8 bq[2];
    #pragma unroll
    for (int no = 0; no < 2; ++no)
      #pragma unroll
      for (int j = 0; j < 8; ++j)
        bq[no][j] = bfs(Wq3[(g*8+j)*32 + no*16 + m]);
    bf16x8 bgw[4][2];
    #pragma unroll
    for (int no = 0; no < 4; ++no)
      #pragma unroll
      for (int kf = 0; kf < 2; ++kf)
        #pragma unroll
        for (int j = 0; j < 8; ++j)
          bgw[no][kf][j] = bfs(Wg2[(kf*32 + g*8 + j)*64 + no*16 + m]);
    const float bq3a = bq3[m], bq3b = bq3[16+m];
    float bgb[4];
    #pragma unroll
    for (int no = 0; no < 4; ++no) bgb[no] = bg2[no*16 + m];
    const float invNP = (float)(*bsz) / (float)N;
    const int p_lin = lane >> 2, c0 = (lane & 3) * 8;

    {
        long long pp = p0 + p_lin; if (pp > N-1) pp = N-1;
        float m1v = m1[pp];
        int b = batch_id[pp];
        const float4* bsp = (const float4*)(bsum + b*32 + c0);
        float4 bs0 = bsp[0], bs1 = bsp[1];
        const float4* s12p = (const float4*)(s12 + pp*32 + c0);
        float4 s0 = s12p[0], s1 = s12p[1];
        float bsv[8] = {bs0.x,bs0.y,bs0.z,bs0.w,bs1.x,bs1.y,bs1.z,bs1.w};
        float sv[8]  = {s0.x,s0.y,s0.z,s0.w,s1.x,s1.y,s1.z,s1.w};
        bf16x8 fbv;
        #pragma unroll
        for (int j = 0; j < 8; ++j) {
            float enc = sqrtf(m1v * bsv[j] * invNP + 1e-12f);
            fbv[j] = bfs(enc + sv[j]);
        }
        *(bf16x8*)&fin_bf[p_lin*40 + c0] = fbv;
    }
    asm volatile("s_waitcnt lgkmcnt(0)" ::: "memory");
    bf16x8 af = *(const bf16x8*)&fin_bf[m*40 + g*8];
    f32x4 f0 = {0.f,0.f,0.f,0.f}, f1 = {0.f,0.f,0.f,0.f};
    f0 = __builtin_amdgcn_mfma_f32_16x16x32_bf16(af, bq[0], f0, 0,0,0);
    f1 = __builtin_amdgcn_mfma_f32_16x16x32_bf16(af, bq[1], f1, 0,0,0);
    #pragma unroll
    for (int j = 0; j < 4; ++j) {
        int row = g*4 + j;
        long long pr = p0 + row; if (pr > N-1) pr = N-1;
        float fa = fmaxf(f0[j] + bq3a, 0.f);
        float fb = fmaxf(f1[j] + bq3b, 0.f);
        float g0 = fmaxf(gl[pr*32 + m] - fa, 0.f);
        float g1 = fmaxf(gl[pr*32 + 16 + m] - fb, 0.f);
        a2_bf[row*72 + 32 + m] = f2bf(g0);
        a2_bf[row*72 + 48 + m] = f2bf(g1);
    }
    asm volatile("s_waitcnt lgkmcnt(0)" ::: "memory");
    bf16x8 a20 = *(const bf16x8*)&a2_bf[m*72 + g*8];
    bf16x8 a21 = *(const bf16x8*)&a2_bf[m*72 + 32 + g*8];
    #pragma unroll
    for (int no = 0; no < 4; ++no) {
        f32x4 acc = {0.f,0.f,0.f,0.f};
        acc = __builtin_amdgcn_mfma_f32_16x16x32_bf16(a20, bgw[no][0], acc, 0,0,0);
        acc = __builtin_amdgcn_mfma_f32_16x16x32_bf16(a21, bgw[no][1], acc, 0,0,0);
        #pragma unroll
        for (int j = 0; j < 4; ++j) {
            long long pr = p0 + g*4 + j;
            if (pr < N)
                out[pr*64 + no*16 + m] = x[pr*64 + no*16 + m] + acc[j] + bgb[no];
        }
    }
}

extern "C" void kernel_launch(void* const* d_in, const int* in_sizes, int n_in,
                              void* d_out, int out_size, void* d_ws, size_t ws_size,
                              hipStream_t stream) {
    const float* x   = (const float*)d_in[0];
    const float* Wg1 = (const float*)d_in[1];
    const float* bg1 = (const float*)d_in[2];
    const float* Wg2 = (const float*)d_in[3];
    const float* bg2 = (const float*)d_in[4];
    const float* Wr1 = (const float*)d_in[5];
    const float* br1 = (const float*)d_in[6];
    const float* Wr2 = (const float*)d_in[7];
    const float* br2 = (const float*)d_in[8];
    const float* Wq1 = (const float*)d_in[9];
    const float* bq1 = (const float*)d_in[10];
    const float* Wq2 = (const float*)d_in[11];
    const float* bq2 = (const float*)d_in[12];
    const float* Wq3 = (const float*)d_in[13];
    const float* bq3 = (const float*)d_in[14];
    const int* nbr   = (const int*)d_in[15];
    const int* bid   = (const int*)d_in[16];
    const int* bsz   = (const int*)d_in[17];

    const long long N = (long long)in_sizes[0] / 64;

    float* cv   = (float*)d_ws;
    float* gl   = cv  + N * 32;
    float* r1   = gl  + N * 32;
    float* s12  = r1  + N * 32;
    float* m1   = s12 + N * 32;
    float* bsum = m1  + N;               // 128 floats used
    u16*   wsB  = (u16*)(bsum + 128);    // 108*512 u16 = 110 KB B-fragments

    float* out = (float*)d_out;

    hipMemsetAsync(bsum, 0, 128 * sizeof(float), stream);

    k0_prep<<<27, 256, 0, stream>>>(Wq1, Wq2, wsB);

    long long tiles = (N + 15) / 16;
    long long gwaves = (tiles + 3) / 4;
    int gblocks = (int)((gwaves + 3) / 4);
    k1_mfma<<<gblocks, 256, 0, stream>>>(x, Wg1, bg1, cv, gl, N);

    long long cwaves = (N + CPT - 1) / CPT;
    int blk8 = (int)((cwaves + 7) / 8);
    k2a_conv<<<blk8, 512, 0, stream>>>(cv, nbr, Wr1, br1, r1, N);
    k2b_mfma<<<768, 256, 0, stream>>>(gl, nbr, bid, wsB, bq1, bq2, s12, m1, bsum, N);
    k3_fused<<<blk8, 512, 0, stream>>>(r1, cv, gl, s12, m1, bsum, nbr, bid,
                                       Wr2, br2, Wq3, bq3, Wg2, bg2, x, out, N, bsz);
}

// Round 13
// 299.198 us; speedup vs baseline: 3.0615x; 1.0634x over previous
//
#include <hip/hip_runtime.h>
#include <stdint.h>

typedef unsigned int u32;
typedef unsigned short u16;
typedef unsigned long long u64;
typedef __attribute__((ext_vector_type(8))) short bf16x8;
typedef __attribute__((ext_vector_type(4))) float f32x4;

#define HC 32
#define KA 10

__device__ __forceinline__ float u2f(u32 u){ union{u32 i;float f;}v; v.i=u; return v.f; }
__device__ __forceinline__ u16 f2bf(float f){ union{float f;u32 i;}v; v.f=f; u32 i=v.i;
    return (u16)((i + 0x7FFFu + ((i>>16)&1u))>>16); }  // RNE
__device__ __forceinline__ short bfs(float f){ return (short)f2bf(f); }
__device__ __forceinline__ u32 packbf(float a, float b){ return (u32)f2bf(a) | ((u32)f2bf(b)<<16); }

// ---- K0: precompute B-fragments for all 4 conv matrices into ws (frag layout, bf16)
// slot = mat*54 + k*2 + oh ; mat: 0=Wq1 1=Wq2 2=Wr1 3=Wr2
// wsB[slot*512 + l*8 + j] = bf16(W[k][(l>>4)*8 + j][oh*16 + (l&15)])
__global__ __launch_bounds__(256) void k0_prep(
    const float* __restrict__ Wq1, const float* __restrict__ Wq2,
    const float* __restrict__ Wr1, const float* __restrict__ Wr2,
    u16* __restrict__ wsB)
{
    int it = blockIdx.x*256 + threadIdx.x;
    if (it >= 216*64) return;
    int l = it & 63, slot = it >> 6;
    int oh = slot & 1, k = (slot >> 1) % 27, mat = slot / 54;
    const float* W = (mat==0)?Wq1:(mat==1)?Wq2:(mat==2)?Wr1:Wr2;
    const float* src = W + k*1024 + oh*16 + (l & 15);
    int crow = (l >> 4) * 8;
    u32 w4[4];
    #pragma unroll
    for (int jj = 0; jj < 4; ++jj)
        w4[jj] = packbf(src[(crow + 2*jj)*32], src[(crow + 2*jj + 1)*32]);
    *(uint4*)&wsB[slot*512 + l*8] = make_uint4(w4[0], w4[1], w4[2], w4[3]);
}

// ---- K1: y = x @ Wg1 + bg1 -> cv | gl  (MFMA) ----
__global__ __launch_bounds__(256) void k1_mfma(
    const float* __restrict__ x, const float* __restrict__ Wg1, const float* __restrict__ bg1,
    float* __restrict__ cv, float* __restrict__ gl, long long N)
{
    const int lane = threadIdx.x & 63;
    const int m = lane & 15, g = lane >> 4;
    bf16x8 bw[4][2];
    #pragma unroll
    for (int no = 0; no < 4; ++no)
      #pragma unroll
      for (int kf = 0; kf < 2; ++kf)
        #pragma unroll
        for (int j = 0; j < 8; ++j)
            bw[no][kf][j] = bfs(Wg1[(kf*32 + g*8 + j)*64 + no*16 + m]);
    float bias4[4];
    #pragma unroll
    for (int no = 0; no < 4; ++no) bias4[no] = bg1[no*16 + m];

    const long long wave = (long long)blockIdx.x*4 + (threadIdx.x>>6);
    long long t0 = wave * 4;
    #pragma unroll 1
    for (long long t = t0; t < t0+4; ++t) {
        long long p0 = t*16;
        if (p0 >= N) break;
        long long pr_a = p0 + m; if (pr_a > N-1) pr_a = N-1;
        const float4* xr = (const float4*)(x + pr_a*64);
        bf16x8 aw[2];
        #pragma unroll
        for (int kf = 0; kf < 2; ++kf) {
            float4 lo = xr[kf*8 + g*2];
            float4 hi = xr[kf*8 + g*2 + 1];
            aw[kf][0]=bfs(lo.x); aw[kf][1]=bfs(lo.y); aw[kf][2]=bfs(lo.z); aw[kf][3]=bfs(lo.w);
            aw[kf][4]=bfs(hi.x); aw[kf][5]=bfs(hi.y); aw[kf][6]=bfs(hi.z); aw[kf][7]=bfs(hi.w);
        }
        #pragma unroll
        for (int no = 0; no < 4; ++no) {
            f32x4 acc = {0.f,0.f,0.f,0.f};
            acc = __builtin_amdgcn_mfma_f32_16x16x32_bf16(aw[0], bw[no][0], acc, 0,0,0);
            acc = __builtin_amdgcn_mfma_f32_16x16x32_bf16(aw[1], bw[no][1], acc, 0,0,0);
            #pragma unroll
            for (int j = 0; j < 4; ++j) {
                long long pr = p0 + g*4 + j;
                if (pr < N) {
                    float v = acc[j] + bias4[no];
                    if (no < 2) cv[pr*32 + no*16 + m] = v;
                    else        gl[pr*32 + (no-2)*16 + m] = v;
                }
            }
        }
    }
}

// ---- shared tile machinery: enumerate valid (k,p) pairs for a 16-point tile ----
// returns np, ns via refs; fills plist/ilist/slist/sstart (per-wave LDS)
__device__ __forceinline__ void enum_tile(
    const int* __restrict__ nbr, long long N, long long p0,
    u16* plist, int* ilist, u16* slist, u16* sstart,
    int lane, u32& np_out, u32& ns_out)
{
    u32 np = 0, ns = 0;
    #pragma unroll
    for (int ch = 0; ch < 7; ++ch) {
        int i = ch*64 + lane;
        int kk = i >> 4, pp = i & 15;
        int ixv = -1;
        if (i < 432 && p0 + pp < N) ixv = nbr[(long long)kk*N + p0 + pp];
        u64 b = __ballot(ixv >= 0);
        u32 kact = 0;
        #pragma unroll
        for (int q2 = 0; q2 < 4; ++q2)
            kact |= ((((b >> (16*q2)) & 0xffffull) != 0ull) ? 1u : 0u) << q2;
        if (ixv >= 0) {
            u64 ltm = (1ull << lane) - 1ull;
            u32 pos = np + (u32)__popcll(b & ltm);
            int q2 = lane >> 4;
            u32 s = ns + __popc(kact & ((1u << q2) - 1u));
            if (pos < 224) {
                plist[pos] = (u16)((s << 9) | (u32)pp);
                ilist[pos] = ixv;
                u64 subm = 0xffffull << (16*q2);
                if ((b & subm & ltm) == 0ull) { slist[s] = (u16)kk; sstart[s] = (u16)pos; }
            }
        }
        np += (u32)__popcll(b);
        ns += __popc(kact);
    }
    if (np > 224) np = 224;
    np_out = np; ns_out = ns;
}

// gather one KA-batch of rows from src into the compacted A buffer
__device__ __forceinline__ void gather_batch(
    const float* __restrict__ src, u16* A,
    const u16* plist, const int* ilist,
    u32 jS, u32 jE, u32 base, int c32, int hf)
{
    uint4 z4 = make_uint4(0u,0u,0u,0u);
    const int lane = (threadIdx.x & 63);
    #pragma unroll
    for (int w = 0; w < 10; ++w) {
        int q = w*64 + lane;
        int r = q / 40, c8 = q - r*40;
        *(uint4*)&A[r*328 + c8*8] = z4;
    }
    asm volatile("s_waitcnt lgkmcnt(0)" ::: "memory");
    for (u32 j0 = jS; j0 < jE; j0 += 16) {
        float v[8]; u32 mt[8];
        #pragma unroll
        for (int tt = 0; tt < 8; ++tt) {
            u32 pj = j0 + 2*tt + (u32)hf;
            bool val = pj < jE;
            u32 pm = val ? (u32)plist[pj] : 0u;
            int ix = val ? ilist[pj] : 0;
            mt[tt] = val ? (pm | 0x80000000u) : 0u;
            v[tt] = val ? src[(long long)ix*32 + c32] : 0.f;
        }
        #pragma unroll
        for (int tt = 0; tt < 8; ++tt) {
            if (mt[tt] >> 31) {
                u32 sl = ((mt[tt] >> 9) & 31u) - base;
                u32 p = mt[tt] & 15u;
                A[p*328 + sl*32 + c32] = f2bf(v[tt]);
            }
        }
    }
    asm volatile("s_waitcnt lgkmcnt(0)" ::: "memory");
}

// ---- K2a: r1 = relu(sconv(cv, Wr1) + br1)  (MFMA tile, Wr1 frags mat=2) ----
__global__ __launch_bounds__(256, 1) void k2a_mfma(
    const float* __restrict__ cv, const int* __restrict__ nbr,
    const u16* __restrict__ wsB, const float* __restrict__ br1,
    float* __restrict__ r1, long long N)
{
    __shared__ __align__(16) u16 Acmp[4][16*328];
    __shared__ u16 plist_s[4][224];
    __shared__ int ilist_s[4][224];
    __shared__ u16 slist_s[4][32];
    __shared__ u16 sstart_s[4][32];

    const int wid = threadIdx.x >> 6;
    const int lane = threadIdx.x & 63;
    const int m = lane & 15, g = lane >> 4;
    const int c32 = lane & 31, hf = lane >> 5;
    u16* A = Acmp[wid];
    u16* plist = plist_s[wid];
    int* ilist = ilist_s[wid];
    u16* slist = slist_s[wid];
    u16* sstart = sstart_s[wid];
    const float b0 = br1[m], b1 = br1[16+m];

    const long long ntiles = (N + 15) >> 4;
    for (long long t = (long long)blockIdx.x*4 + wid; t < ntiles; t += (long long)gridDim.x*4) {
        const long long p0 = t*16;
        u32 np, ns;
        enum_tile(nbr, N, p0, plist, ilist, slist, sstart, lane, np, ns);
        f32x4 acc0 = {0.f,0.f,0.f,0.f}, acc1 = {0.f,0.f,0.f,0.f};
        asm volatile("s_waitcnt lgkmcnt(0)" ::: "memory");
        for (u32 base = 0; base < ns; base += KA) {
            u32 sEnd = base + KA; if (sEnd > ns) sEnd = ns;
            u32 jS = sstart[base];
            u32 jE = (sEnd < ns) ? (u32)sstart[sEnd] : np;
            gather_batch(cv, A, plist, ilist, jS, jE, base, c32, hf);
            for (u32 s = base; s < sEnd; ++s) {
                int sl = (int)(s - base);
                int k = slist[s];
                bf16x8 af = *(const bf16x8*)&A[m*328 + sl*32 + g*8];
                bf16x8 w0 = *(const bf16x8*)&wsB[(108 + k*2 + 0)*512 + lane*8];
                bf16x8 w1 = *(const bf16x8*)&wsB[(108 + k*2 + 1)*512 + lane*8];
                acc0 = __builtin_amdgcn_mfma_f32_16x16x32_bf16(af, w0, acc0, 0,0,0);
                acc1 = __builtin_amdgcn_mfma_f32_16x16x32_bf16(af, w1, acc1, 0,0,0);
            }
        }
        #pragma unroll
        for (int j = 0; j < 4; ++j) {
            long long pr = p0 + g*4 + j;
            if (pr < N) {
                r1[pr*32 + m]      = fmaxf(acc0[j] + b0, 0.f);
                r1[pr*32 + 16 + m] = fmaxf(acc1[j] + b1, 0.f);
            }
        }
    }
}

// ---- K2b: q-convs (MFMA tile, Wq1/Wq2 frags mat=0/1) — round-12 proven ----
__global__ __launch_bounds__(256, 1) void k2b_mfma(
    const float* __restrict__ gl, const int* __restrict__ nbr,
    const int* __restrict__ batch_id, const u16* __restrict__ wsB,
    const float* __restrict__ bq1, const float* __restrict__ bq2,
    float* __restrict__ s12, float* __restrict__ m1, float* __restrict__ bsum,
    long long N)
{
    __shared__ __align__(16) u16 Acmp[4][16*328];
    __shared__ u16 plist_s[4][224];
    __shared__ int ilist_s[4][224];
    __shared__ u16 slist_s[4][32];
    __shared__ u16 sstart_s[4][32];
    __shared__ float lbs[128];

    if (threadIdx.x < 128) lbs[threadIdx.x] = 0.f;
    __syncthreads();

    const int wid = threadIdx.x >> 6;
    const int lane = threadIdx.x & 63;
    const int m = lane & 15, g = lane >> 4;
    const int c32 = lane & 31, hf = lane >> 5;
    u16* A = Acmp[wid];
    u16* plist = plist_s[wid];
    int* ilist = ilist_s[wid];
    u16* slist = slist_s[wid];
    u16* sstart = sstart_s[wid];

    const float b1a = bq1[m], b1b = bq1[16+m], b2a = bq2[m], b2b = bq2[16+m];

    const long long ntiles = (N + 15) >> 4;
    for (long long t = (long long)blockIdx.x*4 + wid; t < ntiles; t += (long long)gridDim.x*4) {
        const long long p0 = t*16;
        u32 np, ns;
        enum_tile(nbr, N, p0, plist, ilist, slist, sstart, lane, np, ns);
        f32x4 acc10 = {0.f,0.f,0.f,0.f}, acc11 = {0.f,0.f,0.f,0.f};
        f32x4 acc20 = {0.f,0.f,0.f,0.f}, acc21 = {0.f,0.f,0.f,0.f};
        asm volatile("s_waitcnt lgkmcnt(0)" ::: "memory");
        for (u32 base = 0; base < ns; base += KA) {
            u32 sEnd = base + KA; if (sEnd > ns) sEnd = ns;
            u32 jS = sstart[base];
            u32 jE = (sEnd < ns) ? (u32)sstart[sEnd] : np;
            gather_batch(gl, A, plist, ilist, jS, jE, base, c32, hf);
            for (u32 s = base; s < sEnd; ++s) {
                int sl = (int)(s - base);
                int k = slist[s];
                bf16x8 af  = *(const bf16x8*)&A[m*328 + sl*32 + g*8];
                bf16x8 w10 = *(const bf16x8*)&wsB[(k*2 + 0)*512 + lane*8];
                bf16x8 w11 = *(const bf16x8*)&wsB[(k*2 + 1)*512 + lane*8];
                bf16x8 w20 = *(const bf16x8*)&wsB[(54 + k*2 + 0)*512 + lane*8];
                bf16x8 w21 = *(const bf16x8*)&wsB[(54 + k*2 + 1)*512 + lane*8];
                acc10 = __builtin_amdgcn_mfma_f32_16x16x32_bf16(af, w10, acc10, 0,0,0);
                acc11 = __builtin_amdgcn_mfma_f32_16x16x32_bf16(af, w11, acc11, 0,0,0);
                acc20 = __builtin_amdgcn_mfma_f32_16x16x32_bf16(af, w20, acc20, 0,0,0);
                acc21 = __builtin_amdgcn_mfma_f32_16x16x32_bf16(af, w21, acc21, 0,0,0);
            }
        }
        #pragma unroll
        for (int j = 0; j < 4; ++j) {
            long long pr = p0 + g*4 + j;
            if (pr < N) {
                float o1a = fmaxf(acc10[j] + b1a, 0.f);
                float o1b = fmaxf(acc11[j] + b1b, 0.f);
                float o2a = fmaxf(acc20[j] + b2a, 0.f);
                float o2b = fmaxf(acc21[j] + b2b, 0.f);
                s12[pr*32 + m]      = o1a + o2a;
                s12[pr*32 + 16 + m] = o1b + o2b;
                float rs = o1a + o1b;
                #pragma unroll
                for (int d = 1; d < 16; d <<= 1) rs += __shfl_xor(rs, d, 64);
                if (m == 0) m1[pr] = rs * (1.f/32.f);
                int bb = batch_id[pr];
                atomicAdd(&lbs[bb*32 + m], o2a);
                atomicAdd(&lbs[bb*32 + 16 + m], o2b);
            }
        }
    }
    __syncthreads();
    if (threadIdx.x < 128) atomicAdd(&bsum[threadIdx.x], lbs[threadIdx.x]);
}

// ---- K3: r2-conv (MFMA tile, Wr2 frags mat=3) -> cx2 -> MFMA epilogue -> out ----
__global__ __launch_bounds__(256, 1) void k3_mfma(
    const float* __restrict__ r1, const float* __restrict__ cv,
    const float* __restrict__ gl, const float* __restrict__ s12,
    const float* __restrict__ m1, const float* __restrict__ bsum,
    const int* __restrict__ nbr, const int* __restrict__ batch_id,
    const u16* __restrict__ wsB, const float* __restrict__ br2,
    const float* __restrict__ Wq3, const float* __restrict__ bq3,
    const float* __restrict__ Wg2, const float* __restrict__ bg2,
    const float* __restrict__ x, float* __restrict__ out,
    long long N, const int* __restrict__ bsz)
{
    __shared__ __align__(16) u16 Acmp[4][16*328];
    __shared__ u16 plist_s[4][224];
    __shared__ int ilist_s[4][224];
    __shared__ u16 slist_s[4][32];
    __shared__ u16 sstart_s[4][32];
    __shared__ __align__(16) u16 finL[4][16*40];
    __shared__ __align__(16) u16 a2L[4][16*72];

    const int wid = threadIdx.x >> 6;
    const int lane = threadIdx.x & 63;
    const int m = lane & 15, g = lane >> 4;
    const int c32 = lane & 31, hf = lane >> 5;
    u16* A = Acmp[wid];
    u16* plist = plist_s[wid];
    int* ilist = ilist_s[wid];
    u16* slist = slist_s[wid];
    u16* sstart = sstart_s[wid];
    u16* fin_bf = finL[wid];
    u16* a2_bf  = a2L[wid];

    // epilogue weights in regs
    bf16x8 bq[2];
    #pragma unroll
    for (int no = 0; no < 2; ++no)
      #pragma unroll
      for (int j = 0; j < 8; ++j)
        bq[no][j] = bfs(Wq3[(g*8+j)*32 + no*16 + m]);
    bf16x8 bgw[4][2];
    #pragma unroll
    for (int no = 0; no < 4; ++no)
      #pragma unroll
      for (int kf = 0; kf < 2; ++kf)
        #pragma unroll
        for (int j = 0; j < 8; ++j)
          bgw[no][kf][j] = bfs(Wg2[(kf*32 + g*8 + j)*64 + no*16 + m]);
    const float br2a = br2[m], br2b = br2[16+m];
    const float bq3a = bq3[m], bq3b = bq3[16+m];
    float bgb[4];
    #pragma unroll
    for (int no = 0; no < 4; ++no) bgb[no] = bg2[no*16 + m];
    const float invNP = (float)(*bsz) / (float)N;
    const int p_lin = lane >> 2, c0 = (lane & 3) * 8;

    const long long ntiles = (N + 15) >> 4;
    for (long long t = (long long)blockIdx.x*4 + wid; t < ntiles; t += (long long)gridDim.x*4) {
        const long long p0 = t*16;
        // ---- conv phase: acc = sconv(r1, Wr2) ----
        u32 np, ns;
        enum_tile(nbr, N, p0, plist, ilist, slist, sstart, lane, np, ns);
        f32x4 acc0 = {0.f,0.f,0.f,0.f}, acc1 = {0.f,0.f,0.f,0.f};
        asm volatile("s_waitcnt lgkmcnt(0)" ::: "memory");
        for (u32 base = 0; base < ns; base += KA) {
            u32 sEnd = base + KA; if (sEnd > ns) sEnd = ns;
            u32 jS = sstart[base];
            u32 jE = (sEnd < ns) ? (u32)sstart[sEnd] : np;
            gather_batch(r1, A, plist, ilist, jS, jE, base, c32, hf);
            for (u32 s = base; s < sEnd; ++s) {
                int sl = (int)(s - base);
                int k = slist[s];
                bf16x8 af = *(const bf16x8*)&A[m*328 + sl*32 + g*8];
                bf16x8 w0 = *(const bf16x8*)&wsB[(162 + k*2 + 0)*512 + lane*8];
                bf16x8 w1 = *(const bf16x8*)&wsB[(162 + k*2 + 1)*512 + lane*8];
                acc0 = __builtin_amdgcn_mfma_f32_16x16x32_bf16(af, w0, acc0, 0,0,0);
                acc1 = __builtin_amdgcn_mfma_f32_16x16x32_bf16(af, w1, acc1, 0,0,0);
            }
        }
        // cx2 = relu(acc + br2) + 2*cv  -> a2 tile (bf16, C-layout rows)
        #pragma unroll
        for (int j = 0; j < 4; ++j) {
            int row = g*4 + j;
            long long pr = p0 + row; if (pr > N-1) pr = N-1;
            float cxa = fmaxf(acc0[j] + br2a, 0.f) + 2.f*cv[pr*32 + m];
            float cxb = fmaxf(acc1[j] + br2b, 0.f) + 2.f*cv[pr*32 + 16 + m];
            a2_bf[row*72 + m]      = f2bf(cxa);
            a2_bf[row*72 + 16 + m] = f2bf(cxb);
        }
        // ---- epilogue ----
        {
            long long pp = p0 + p_lin; if (pp > N-1) pp = N-1;
            float m1v = m1[pp];
            int b = batch_id[pp];
            const float4* bsp = (const float4*)(bsum + b*32 + c0);
            float4 bs0 = bsp[0], bs1 = bsp[1];
            const float4* s12p = (const float4*)(s12 + pp*32 + c0);
            float4 s0 = s12p[0], s1 = s12p[1];
            float bsv[8] = {bs0.x,bs0.y,bs0.z,bs0.w,bs1.x,bs1.y,bs1.z,bs1.w};
            float sv[8]  = {s0.x,s0.y,s0.z,s0.w,s1.x,s1.y,s1.z,s1.w};
            bf16x8 fbv;
            #pragma unroll
            for (int j = 0; j < 8; ++j) {
                float enc = sqrtf(m1v * bsv[j] * invNP + 1e-12f);
                fbv[j] = bfs(enc + sv[j]);
            }
            *(bf16x8*)&fin_bf[p_lin*40 + c0] = fbv;
        }
        asm volatile("s_waitcnt lgkmcnt(0)" ::: "memory");
        bf16x8 af2 = *(const bf16x8*)&fin_bf[m*40 + g*8];
        f32x4 f0 = {0.f,0.f,0.f,0.f}, f1 = {0.f,0.f,0.f,0.f};
        f0 = __builtin_amdgcn_mfma_f32_16x16x32_bf16(af2, bq[0], f0, 0,0,0);
        f1 = __builtin_amdgcn_mfma_f32_16x16x32_bf16(af2, bq[1], f1, 0,0,0);
        #pragma unroll
        for (int j = 0; j < 4; ++j) {
            int row = g*4 + j;
            long long pr = p0 + row; if (pr > N-1) pr = N-1;
            float fa = fmaxf(f0[j] + bq3a, 0.f);
            float fb = fmaxf(f1[j] + bq3b, 0.f);
            float g0 = fmaxf(gl[pr*32 + m] - fa, 0.f);
            float g1 = fmaxf(gl[pr*32 + 16 + m] - fb, 0.f);
            a2_bf[row*72 + 32 + m] = f2bf(g0);
            a2_bf[row*72 + 48 + m] = f2bf(g1);
        }
        asm volatile("s_waitcnt lgkmcnt(0)" ::: "memory");
        bf16x8 a20 = *(const bf16x8*)&a2_bf[m*72 + g*8];
        bf16x8 a21 = *(const bf16x8*)&a2_bf[m*72 + 32 + g*8];
        #pragma unroll
        for (int no = 0; no < 4; ++no) {
            f32x4 acc = {0.f,0.f,0.f,0.f};
            acc = __builtin_amdgcn_mfma_f32_16x16x32_bf16(a20, bgw[no][0], acc, 0,0,0);
            acc = __builtin_amdgcn_mfma_f32_16x16x32_bf16(a21, bgw[no][1], acc, 0,0,0);
            #pragma unroll
            for (int j = 0; j < 4; ++j) {
                long long pr = p0 + g*4 + j;
                if (pr < N)
                    out[pr*64 + no*16 + m] = x[pr*64 + no*16 + m] + acc[j] + bgb[no];
            }
        }
    }
}

extern "C" void kernel_launch(void* const* d_in, const int* in_sizes, int n_in,
                              void* d_out, int out_size, void* d_ws, size_t ws_size,
                              hipStream_t stream) {
    const float* x   = (const float*)d_in[0];
    const float* Wg1 = (const float*)d_in[1];
    const float* bg1 = (const float*)d_in[2];
    const float* Wg2 = (const float*)d_in[3];
    const float* bg2 = (const float*)d_in[4];
    const float* Wr1 = (const float*)d_in[5];
    const float* br1 = (const float*)d_in[6];
    const float* Wr2 = (const float*)d_in[7];
    const float* br2 = (const float*)d_in[8];
    const float* Wq1 = (const float*)d_in[9];
    const float* bq1 = (const float*)d_in[10];
    const float* Wq2 = (const float*)d_in[11];
    const float* bq2 = (const float*)d_in[12];
    const float* Wq3 = (const float*)d_in[13];
    const float* bq3 = (const float*)d_in[14];
    const int* nbr   = (const int*)d_in[15];
    const int* bid   = (const int*)d_in[16];
    const int* bsz   = (const int*)d_in[17];

    const long long N = (long long)in_sizes[0] / 64;

    float* cv   = (float*)d_ws;
    float* gl   = cv  + N * 32;
    float* r1   = gl  + N * 32;
    float* s12  = r1  + N * 32;
    float* m1   = s12 + N * 32;
    float* bsum = m1  + N;               // 128 floats used
    u16*   wsB  = (u16*)(bsum + 128);    // 216*512 u16 = 221 KB B-fragments

    float* out = (float*)d_out;

    hipMemsetAsync(bsum, 0, 128 * sizeof(float), stream);

    k0_prep<<<54, 256, 0, stream>>>(Wq1, Wq2, Wr1, Wr2, wsB);

    long long tiles = (N + 15) / 16;
    long long gwaves = (tiles + 3) / 4;
    int gblocks = (int)((gwaves + 3) / 4);
    k1_mfma<<<gblocks, 256, 0, stream>>>(x, Wg1, bg1, cv, gl, N);

    k2a_mfma<<<768, 256, 0, stream>>>(cv, nbr, wsB, br1, r1, N);
    k2b_mfma<<<768, 256, 0, stream>>>(gl, nbr, bid, wsB, bq1, bq2, s12, m1, bsum, N);
    k3_mfma<<<768, 256, 0, stream>>>(r1, cv, gl, s12, m1, bsum, nbr, bid, wsB, br2,
                                     Wq3, bq3, Wg2, bg2, x, out, N, bsz);
}